// Round 4
// baseline (589.142 us; speedup 1.0000x reference)
//
#include <hip/hip_runtime.h>

#define THREADS 256
#define BNODES 256           // nodes per dst-bucket
#define PACK_SHIFT 20        // src in low 20 bits, local dst in high bits

// ---------------- CSR build (binned counting sort) ----------------

// A0: node histogram + per-(group, bucket) histogram. g = blockIdx&7 must match A1.
__global__ void hist2_kernel(const int* __restrict__ dst, int* __restrict__ cnt,
                             int* __restrict__ subcnt, int NB, int E) {
    int e = blockIdx.x * blockDim.x + threadIdx.x;
    if (e < E) {
        int d = dst[e];
        atomicAdd(&cnt[d], 1);
        atomicAdd(&subcnt[(blockIdx.x & 7) * NB + (d >> 8)], 1);
    }
}

__global__ void dis_kernel(const int* __restrict__ cnt, float* __restrict__ dis, int N) {
    int i = blockIdx.x * blockDim.x + threadIdx.x;
    if (i < N) dis[i] = rsqrtf((float)cnt[i] + 1.0f);  // +1 self-loop
}

// block-local inclusive scan of cnt -> rowptr[i+1]; block totals -> bsum[b]
__global__ void scan_block_kernel(const int* __restrict__ cnt, int* __restrict__ rowptr,
                                  int* __restrict__ bsum, int N) {
    __shared__ int sh[1024];
    int t = threadIdx.x;
    int i = blockIdx.x * 1024 + t;
    sh[t] = (i < N) ? cnt[i] : 0;
    __syncthreads();
    for (int off = 1; off < 1024; off <<= 1) {
        int add = (t >= off) ? sh[t - off] : 0;
        __syncthreads();
        sh[t] += add;
        __syncthreads();
    }
    if (i < N) rowptr[i + 1] = sh[t];
    if (t == 1023) bsum[blockIdx.x] = sh[t];
}

// single-block exclusive scan of bsum (nb <= 1024)
__global__ void scan_partials_kernel(int* __restrict__ bsum, int nb) {
    __shared__ int sh[1024];
    int t = threadIdx.x;
    int v = (t < nb) ? bsum[t] : 0;
    sh[t] = v;
    __syncthreads();
    for (int off = 1; off < 1024; off <<= 1) {
        int add = (t >= off) ? sh[t - off] : 0;
        __syncthreads();
        sh[t] += add;
        __syncthreads();
    }
    if (t < nb) bsum[t] = sh[t] - v;  // exclusive
}

__global__ void scan_add_kernel(int* __restrict__ rowptr, const int* __restrict__ bsum, int N) {
    int i = blockIdx.x * blockDim.x + threadIdx.x;
    if (i < N) {
        rowptr[i + 1] += bsum[i >> 10];
        if (i == 0) rowptr[0] = 0;
    }
}

// A1: append packed (src, local_dst) into (g, bucket) sub-segment (dense writes).
__global__ void bin_scatter_kernel(const int* __restrict__ src, const int* __restrict__ dst,
                                   const int* __restrict__ subptr, int* __restrict__ subcur,
                                   int* __restrict__ ebuf, int NB, int E) {
    int e = blockIdx.x * blockDim.x + threadIdx.x;
    if (e < E) {
        int d = dst[e];
        int idx = (blockIdx.x & 7) * NB + (d >> 8);
        int pos = subptr[idx] + atomicAdd(&subcur[idx], 1);
        ebuf[pos] = src[e] | ((d & (BNODES - 1)) << PACK_SHIFT);
    }
}

// B: one workgroup per bucket: order edges via LDS cursors, write srcs into a
// contiguous window (single-XCD-owned lines).
__global__ __launch_bounds__(256) void bin_fill_kernel(const int* __restrict__ ebuf,
                                                       const int* __restrict__ subptr,
                                                       const int* __restrict__ rowptr,
                                                       int* __restrict__ srcs, int NB, int N) {
    __shared__ int cur[BNODES];
    __shared__ int rpt[BNODES];
    int b = blockIdx.x;
    int t = threadIdx.x;
    int base = b * BNODES;
    cur[t] = 0;
    if (base + t < N) rpt[t] = rowptr[base + t];
    __syncthreads();
    const int mask = (1 << PACK_SHIFT) - 1;
    for (int g = 0; g < 8; ++g) {
        int idx = g * NB + b;
        int s = subptr[idx], e = subptr[idx + 1];
        for (int i = s + t; i < e; i += 256) {
            int w = ebuf[i];
            int sn = w & mask;
            int local = ((unsigned)w) >> PACK_SHIFT;
            int pos = rpt[local] + atomicAdd(&cur[local], 1);
            srcs[pos] = sn;
        }
    }
}

// ---------------- tiled GEMM ----------------
// Y[M,64] = X[M,K] @ W[K,64], optional row-scale by dis[row].
template<int K, bool SCALE>
__global__ __launch_bounds__(256) void gemm_tiled(const float* __restrict__ X,
                                                  const float* __restrict__ W,
                                                  const float* __restrict__ dis,
                                                  float* __restrict__ Y, int M) {
    __shared__ float Ws[K * 64];
    __shared__ float Xs[32 * 68];
    const int t = threadIdx.x;

    for (int i = t; i < K * 16; i += THREADS)
        ((float4*)Ws)[i] = ((const float4*)W)[i];

    const int r0 = blockIdx.x * 64;
    const int wave = t >> 6;
    const int lane = t & 63;
    const int tr = lane & 15;
    const int tc = (lane >> 4) + wave * 4;

    float acc[4][4] = {};

    for (int kc = 0; kc < K; kc += 32) {
        __syncthreads();
        #pragma unroll
        for (int i = t; i < 512; i += THREADS) {
            int row = i >> 3;
            int kq = i & 7;
            int gr = r0 + row;
            if (gr >= M) gr = M - 1;
            float4 v = *(const float4*)(X + (size_t)gr * K + kc + kq * 4);
            Xs[(kq * 4 + 0) * 68 + row] = v.x;
            Xs[(kq * 4 + 1) * 68 + row] = v.y;
            Xs[(kq * 4 + 2) * 68 + row] = v.z;
            Xs[(kq * 4 + 3) * 68 + row] = v.w;
        }
        __syncthreads();
        #pragma unroll
        for (int kk = 0; kk < 32; ++kk) {
            float4 xv = *(const float4*)(Xs + kk * 68 + tr * 4);
            float4 wv = *(const float4*)(Ws + (kc + kk) * 64 + tc * 4);
            acc[0][0] = fmaf(xv.x, wv.x, acc[0][0]);
            acc[0][1] = fmaf(xv.x, wv.y, acc[0][1]);
            acc[0][2] = fmaf(xv.x, wv.z, acc[0][2]);
            acc[0][3] = fmaf(xv.x, wv.w, acc[0][3]);
            acc[1][0] = fmaf(xv.y, wv.x, acc[1][0]);
            acc[1][1] = fmaf(xv.y, wv.y, acc[1][1]);
            acc[1][2] = fmaf(xv.y, wv.z, acc[1][2]);
            acc[1][3] = fmaf(xv.y, wv.w, acc[1][3]);
            acc[2][0] = fmaf(xv.z, wv.x, acc[2][0]);
            acc[2][1] = fmaf(xv.z, wv.y, acc[2][1]);
            acc[2][2] = fmaf(xv.z, wv.z, acc[2][2]);
            acc[2][3] = fmaf(xv.z, wv.w, acc[2][3]);
            acc[3][0] = fmaf(xv.w, wv.x, acc[3][0]);
            acc[3][1] = fmaf(xv.w, wv.y, acc[3][1]);
            acc[3][2] = fmaf(xv.w, wv.z, acc[3][2]);
            acc[3][3] = fmaf(xv.w, wv.w, acc[3][3]);
        }
    }

    #pragma unroll
    for (int i = 0; i < 4; ++i) {
        int row = r0 + tr * 4 + i;
        if (row < M) {
            float s = SCALE ? dis[row] : 1.0f;
            float4 st = make_float4(acc[i][0] * s, acc[i][1] * s, acc[i][2] * s, acc[i][3] * s);
            *(float4*)(Y + (size_t)row * 64 + tc * 4) = st;
        }
    }
}

// ---------------- pull aggregate ----------------
__global__ void pull_kernel(const float* __restrict__ hpre, const int* __restrict__ rowptr,
                            const int* __restrict__ srcs, const float* __restrict__ dis,
                            const float* __restrict__ b, float* __restrict__ out, int N) {
    int tid = threadIdx.x;
    int node = blockIdx.x * 4 + (tid >> 6);
    if (node >= N) return;
    int lane = tid & 63;
    float acc = hpre[(size_t)node * 64 + lane];  // self loop
    int i = rowptr[node], end = rowptr[node + 1];
    for (; i + 4 <= end; i += 4) {
        int s0 = srcs[i], s1 = srcs[i + 1], s2 = srcs[i + 2], s3 = srcs[i + 3];
        float v0 = hpre[(size_t)s0 * 64 + lane];
        float v1 = hpre[(size_t)s1 * 64 + lane];
        float v2 = hpre[(size_t)s2 * 64 + lane];
        float v3 = hpre[(size_t)s3 * 64 + lane];
        acc += v0 + v1 + v2 + v3;
    }
    for (; i < end; ++i) acc += hpre[(size_t)srcs[i] * 64 + lane];
    float o = acc * dis[node] + b[lane];
    out[(size_t)node * 64 + lane] = o > 0.f ? o : 0.f;
}

// ---------------- head ----------------
__global__ void head_kernel(const float* __restrict__ h, const int* __restrict__ pairs,
                            const float* __restrict__ Wh, const float* __restrict__ bh,
                            float* __restrict__ out, int P) {
    long long idx = (long long)blockIdx.x * blockDim.x + threadIdx.x;
    int p = (int)(idx >> 6);
    int lane = threadIdx.x & 63;
    if (p >= P) return;
    int p0 = pairs[2 * (size_t)p];
    int p1 = pairs[2 * (size_t)p + 1];
    float v = h[(size_t)p0 * 64 + lane] * Wh[lane]
            + h[(size_t)p1 * 64 + lane] * Wh[64 + lane];
    #pragma unroll
    for (int off = 32; off > 0; off >>= 1) v += __shfl_down(v, off);
    if (lane == 0) out[p] = v + bh[0];
}

// ---------------- fallback (atomic push) ----------------
__global__ void degf_kernel(const int* __restrict__ dst, float* __restrict__ deg, int E) {
    int e = blockIdx.x * blockDim.x + threadIdx.x;
    if (e < E) atomicAdd(&deg[dst[e]], 1.0f);
}
__global__ void rsqrtf_kernel(float* deg, int N) {
    int i = blockIdx.x * blockDim.x + threadIdx.x;
    if (i < N) deg[i] = rsqrtf(deg[i] + 1.0f);
}
__global__ void scatter_kernel(const float* __restrict__ h, const int* __restrict__ src,
                               const int* __restrict__ dst, const float* __restrict__ dis,
                               float* __restrict__ agg, int E, int N) {
    long long idx = (long long)blockIdx.x * blockDim.x + threadIdx.x;
    int e = (int)(idx >> 6);
    int f = (int)(idx & 63);
    if (e >= E + N) return;
    int s, d;
    if (e < E) { s = src[e]; d = dst[e]; } else { s = e - E; d = s; }
    float norm = dis[s] * dis[d];
    atomicAdd(&agg[(size_t)d * 64 + f], h[(size_t)s * 64 + f] * norm);
}
__global__ void bias_relu_kernel(float* __restrict__ buf, const float* __restrict__ b,
                                 long long total) {
    long long i = (long long)blockIdx.x * blockDim.x + threadIdx.x;
    if (i < total) {
        float v = buf[i] + b[(int)(i & 63)];
        buf[i] = v > 0.f ? v : 0.f;
    }
}

extern "C" void kernel_launch(void* const* d_in, const int* in_sizes, int n_in,
                              void* d_out, int out_size, void* d_ws, size_t ws_size,
                              hipStream_t stream) {
    const float* x     = (const float*)d_in[0];
    const int*   ei    = (const int*)d_in[1];   // [2,E]: row0=src, row1=dst
    const int*   pairs = (const int*)d_in[3];   // [P,2]
    const float* W1    = (const float*)d_in[4];
    const float* b1    = (const float*)d_in[5];
    const float* W2    = (const float*)d_in[6];
    const float* b2    = (const float*)d_in[7];
    const float* Wh    = (const float*)d_in[8];
    const float* bh    = (const float*)d_in[9];

    const int N = in_sizes[0] / 128;
    const int E = in_sizes[1] / 2;
    const int P = in_sizes[3] / 2;
    const int* srcArr = ei;
    const int* dstArr = ei + E;

    const size_t feat_total = (size_t)N * 64;
    const int nbScan = (N + 1023) / 1024;
    const int NB = (N + BNODES - 1) / BNODES;   // dst buckets
    const int NB8 = NB * 8;                     // (group, bucket) sub-buckets
    const int nbScan2 = (NB8 + 1023) / 1024;
    const int gemm_blocks = (N + 63) / 64;
    const int eblocks = (E + THREADS - 1) / THREADS;

    auto align512 = [](size_t v) { return (v + 511) & ~(size_t)511; };

    char* ws = (char*)d_ws;
    size_t off = 0;
    float* dis    = (float*)(ws + off); off += align512((size_t)N * 4);
    int*   cnt    = (int*)  (ws + off); off += align512((size_t)N * 4);
    int*   rowptr = (int*)  (ws + off); off += align512(((size_t)N + 1) * 4);
    int*   bsum   = (int*)  (ws + off); off += align512((size_t)nbScan * 4);
    int*   subcnt = (int*)  (ws + off); off += align512((size_t)NB8 * 4);
    int*   subcur = (int*)  (ws + off); off += align512((size_t)NB8 * 4);
    int*   subptr = (int*)  (ws + off); off += align512(((size_t)NB8 + 1) * 4);
    int*   bsum2  = (int*)  (ws + off); off += align512((size_t)nbScan2 * 4);
    int*   srcs   = (int*)  (ws + off); off += align512((size_t)E * 4);
    float* bufA   = (float*)(ws + off); off += align512(feat_total * 4);
    float* bufB   = (float*)(ws + off); off += align512(feat_total * 4);
    int*   ebuf   = (int*)bufA;  // aliased: consumed by bin_fill before gemm1 writes bufA
    const bool csr_ok = (off <= ws_size) && (nbScan <= 1024) && (nbScan2 <= 1024) &&
                        (N <= (1 << PACK_SHIFT)) && ((size_t)E * 4 <= feat_total * 4);

    if (csr_ok) {
        // ---- histograms ----
        hipMemsetAsync(cnt, 0, (size_t)N * 4, stream);
        hipMemsetAsync(subcnt, 0, (size_t)NB8 * 4, stream);
        hipMemsetAsync(subcur, 0, (size_t)NB8 * 4, stream);
        hist2_kernel<<<eblocks, THREADS, 0, stream>>>(dstArr, cnt, subcnt, NB, E);
        dis_kernel<<<(N + THREADS - 1) / THREADS, THREADS, 0, stream>>>(cnt, dis, N);
        // ---- scans: rowptr (nodes), subptr (sub-buckets) ----
        scan_block_kernel<<<nbScan, 1024, 0, stream>>>(cnt, rowptr, bsum, N);
        scan_partials_kernel<<<1, 1024, 0, stream>>>(bsum, nbScan);
        scan_add_kernel<<<(N + THREADS - 1) / THREADS, THREADS, 0, stream>>>(rowptr, bsum, N);
        scan_block_kernel<<<nbScan2, 1024, 0, stream>>>(subcnt, subptr, bsum2, NB8);
        scan_partials_kernel<<<1, 1024, 0, stream>>>(bsum2, nbScan2);
        scan_add_kernel<<<(NB8 + THREADS - 1) / THREADS, THREADS, 0, stream>>>(subptr, bsum2, NB8);
        // ---- bin + ordered fill ----
        bin_scatter_kernel<<<eblocks, THREADS, 0, stream>>>(srcArr, dstArr, subptr, subcur,
                                                            ebuf, NB, E);
        bin_fill_kernel<<<NB, 256, 0, stream>>>(ebuf, subptr, rowptr, srcs, NB, N);

        // ---- layer 1 ----
        gemm_tiled<128, true><<<gemm_blocks, THREADS, 0, stream>>>(x, W1, dis, bufA, N);
        pull_kernel<<<(N + 3) / 4, THREADS, 0, stream>>>(bufA, rowptr, srcs, dis, b1, bufB, N);

        // ---- layer 2 ----
        gemm_tiled<64, true><<<gemm_blocks, THREADS, 0, stream>>>(bufB, W2, dis, bufA, N);
        pull_kernel<<<(N + 3) / 4, THREADS, 0, stream>>>(bufA, rowptr, srcs, dis, b2, bufB, N);

        // ---- head ----
        head_kernel<<<(unsigned)(((size_t)P * 64 + THREADS - 1) / THREADS), THREADS, 0, stream>>>(
            bufB, pairs, Wh, bh, (float*)d_out, P);
    } else {
        // ---- fallback: atomic push path ----
        size_t o2 = 0;
        float* deg  = (float*)(ws + o2); o2 += align512((size_t)N * 4);
        float* bA   = (float*)(ws + o2); o2 += align512(feat_total * 4);
        float* bB   = (float*)(ws + o2);
        const size_t edge_threads = (size_t)(E + N) * 64;

        hipMemsetAsync(deg, 0, (size_t)N * 4, stream);
        degf_kernel<<<eblocks, THREADS, 0, stream>>>(dstArr, deg, E);
        rsqrtf_kernel<<<(N + THREADS - 1) / THREADS, THREADS, 0, stream>>>(deg, N);

        gemm_tiled<128, false><<<gemm_blocks, THREADS, 0, stream>>>(x, W1, deg, bA, N);
        hipMemsetAsync(bB, 0, feat_total * 4, stream);
        scatter_kernel<<<(unsigned)((edge_threads + THREADS - 1) / THREADS), THREADS, 0, stream>>>(
            bA, srcArr, dstArr, deg, bB, E, N);
        bias_relu_kernel<<<(unsigned)((feat_total + THREADS - 1) / THREADS), THREADS, 0, stream>>>(
            bB, b1, (long long)feat_total);

        gemm_tiled<64, false><<<gemm_blocks, THREADS, 0, stream>>>(bB, W2, deg, bA, N);
        hipMemsetAsync(bB, 0, feat_total * 4, stream);
        scatter_kernel<<<(unsigned)((edge_threads + THREADS - 1) / THREADS), THREADS, 0, stream>>>(
            bA, srcArr, dstArr, deg, bB, E, N);
        bias_relu_kernel<<<(unsigned)((feat_total + THREADS - 1) / THREADS), THREADS, 0, stream>>>(
            bB, b2, (long long)feat_total);

        head_kernel<<<(unsigned)(((size_t)P * 64 + THREADS - 1) / THREADS), THREADS, 0, stream>>>(
            bB, pairs, Wh, bh, (float*)d_out, P);
    }
}

// Round 5
// 361.977 us; speedup vs baseline: 1.6276x; 1.6276x over previous
//
#include <hip/hip_runtime.h>

#define THREADS 256
#define BNODES 256           // nodes per dst-bucket
#define PACK_SHIFT 20        // src in low 20 bits, local dst in bits 20..27
#define TILE 8192            // edges per block in count/scatter

// ---------------- CSR build: block-binned counting sort, no per-edge global atomics ----

// P1: per-block LDS histogram over buckets, aggregated flush to subcnt.
__global__ __launch_bounds__(256) void count_buckets(const int* __restrict__ dst,
                                                     int* __restrict__ subcnt,
                                                     int NB, int E) {
    __shared__ int h[1024];
    int t = threadIdx.x;
    for (int i = t; i < NB; i += 256) h[i] = 0;
    __syncthreads();
    int e0 = blockIdx.x * TILE;
    int e1 = min(e0 + TILE, E);
    for (int e = e0 + t; e < e1; e += 256)
        atomicAdd(&h[dst[e] >> 8], 1);
    __syncthreads();
    for (int i = t; i < NB; i += 256)
        if (h[i] > 0) atomicAdd(&subcnt[i], h[i]);
}

// exclusive scan of subcnt[0..nb) -> ptr; ptr[nb] = total. nb <= 1024.
__global__ void scan_small_kernel(const int* __restrict__ cnt, int* __restrict__ ptr,
                                  int nb, int total) {
    __shared__ int sh[1024];
    int t = threadIdx.x;
    int v = (t < nb) ? cnt[t] : 0;
    sh[t] = v;
    __syncthreads();
    for (int off = 1; off < 1024; off <<= 1) {
        int add = (t >= off) ? sh[t - off] : 0;
        __syncthreads();
        sh[t] += add;
        __syncthreads();
    }
    if (t < nb) ptr[t] = sh[t] - v;
    if (t == 0) ptr[nb] = total;
}

// P2: re-histogram tile, claim per-bucket base (1 atomic per block-bucket), place
// packed words via LDS cursors -> dense runs inside each bucket segment.
__global__ __launch_bounds__(256) void block_scatter(const int* __restrict__ src,
                                                     const int* __restrict__ dst,
                                                     const int* __restrict__ subptr,
                                                     int* __restrict__ subcur,
                                                     int* __restrict__ ebuf,
                                                     int NB, int E) {
    __shared__ int h[1024];
    __shared__ int bb[1024];
    int t = threadIdx.x;
    for (int i = t; i < NB; i += 256) h[i] = 0;
    __syncthreads();
    int e0 = blockIdx.x * TILE;
    int e1 = min(e0 + TILE, E);
    for (int e = e0 + t; e < e1; e += 256)
        atomicAdd(&h[dst[e] >> 8], 1);
    __syncthreads();
    for (int i = t; i < NB; i += 256) {
        int c = h[i];
        bb[i] = (c > 0) ? (subptr[i] + atomicAdd(&subcur[i], c)) : 0;
        h[i] = 0;  // reuse as cursor
    }
    __syncthreads();
    for (int e = e0 + t; e < e1; e += 256) {
        int d = dst[e];
        int b = d >> 8;
        int pos = bb[b] + atomicAdd(&h[b], 1);
        ebuf[pos] = src[e] | ((d & (BNODES - 1)) << PACK_SHIFT);
    }
}

// B: one block per bucket. Computes node degrees (LDS), writes dis + rowptr (dense),
// then orders edges into srcs within the bucket's contiguous window.
__global__ __launch_bounds__(256) void bin_fill_kernel(const int* __restrict__ ebuf,
                                                       const int* __restrict__ subptr,
                                                       int* __restrict__ rowptr,
                                                       float* __restrict__ dis,
                                                       int* __restrict__ srcs,
                                                       int NB, int N, int E) {
    __shared__ int cntL[BNODES];
    __shared__ int rb[BNODES];
    int b = blockIdx.x;
    int t = threadIdx.x;
    int base = b * BNODES;
    int s0 = subptr[b], s1 = subptr[b + 1];
    cntL[t] = 0;
    __syncthreads();
    for (int i = s0 + t; i < s1; i += 256)
        atomicAdd(&cntL[((unsigned)ebuf[i]) >> PACK_SHIFT], 1);
    __syncthreads();
    int myc = cntL[t];
    if (base + t < N) dis[base + t] = rsqrtf((float)myc + 1.0f);
    // exclusive scan of cntL
    rb[t] = myc;
    __syncthreads();
    #pragma unroll
    for (int off = 1; off < 256; off <<= 1) {
        int add = (t >= off) ? rb[t - off] : 0;
        __syncthreads();
        rb[t] += add;
        __syncthreads();
    }
    int excl = rb[t] - myc;
    rb[t] = s0 + excl;
    if (base + t < N) rowptr[base + t] = s0 + excl;
    if (b == NB - 1 && t == 0) rowptr[N] = E;
    cntL[t] = 0;  // reuse as cursor
    __syncthreads();
    const int mask = (1 << PACK_SHIFT) - 1;
    for (int i = s0 + t; i < s1; i += 256) {
        int w = ebuf[i];
        int local = ((unsigned)w) >> PACK_SHIFT;
        int pos = rb[local] + atomicAdd(&cntL[local], 1);
        srcs[pos] = w & mask;
    }
}

// ---------------- tiled GEMM ----------------
// Y[M,64] = X[M,K] @ W[K,64], optional row-scale by dis[row].
template<int K, bool SCALE>
__global__ __launch_bounds__(256) void gemm_tiled(const float* __restrict__ X,
                                                  const float* __restrict__ W,
                                                  const float* __restrict__ dis,
                                                  float* __restrict__ Y, int M) {
    __shared__ float Ws[K * 64];
    __shared__ float Xs[32 * 68];
    const int t = threadIdx.x;

    for (int i = t; i < K * 16; i += THREADS)
        ((float4*)Ws)[i] = ((const float4*)W)[i];

    const int r0 = blockIdx.x * 64;
    const int wave = t >> 6;
    const int lane = t & 63;
    const int tr = lane & 15;
    const int tc = (lane >> 4) + wave * 4;

    float acc[4][4] = {};

    for (int kc = 0; kc < K; kc += 32) {
        __syncthreads();
        #pragma unroll
        for (int i = t; i < 512; i += THREADS) {
            int row = i >> 3;
            int kq = i & 7;
            int gr = r0 + row;
            if (gr >= M) gr = M - 1;
            float4 v = *(const float4*)(X + (size_t)gr * K + kc + kq * 4);
            Xs[(kq * 4 + 0) * 68 + row] = v.x;
            Xs[(kq * 4 + 1) * 68 + row] = v.y;
            Xs[(kq * 4 + 2) * 68 + row] = v.z;
            Xs[(kq * 4 + 3) * 68 + row] = v.w;
        }
        __syncthreads();
        #pragma unroll
        for (int kk = 0; kk < 32; ++kk) {
            float4 xv = *(const float4*)(Xs + kk * 68 + tr * 4);
            float4 wv = *(const float4*)(Ws + (kc + kk) * 64 + tc * 4);
            acc[0][0] = fmaf(xv.x, wv.x, acc[0][0]);
            acc[0][1] = fmaf(xv.x, wv.y, acc[0][1]);
            acc[0][2] = fmaf(xv.x, wv.z, acc[0][2]);
            acc[0][3] = fmaf(xv.x, wv.w, acc[0][3]);
            acc[1][0] = fmaf(xv.y, wv.x, acc[1][0]);
            acc[1][1] = fmaf(xv.y, wv.y, acc[1][1]);
            acc[1][2] = fmaf(xv.y, wv.z, acc[1][2]);
            acc[1][3] = fmaf(xv.y, wv.w, acc[1][3]);
            acc[2][0] = fmaf(xv.z, wv.x, acc[2][0]);
            acc[2][1] = fmaf(xv.z, wv.y, acc[2][1]);
            acc[2][2] = fmaf(xv.z, wv.z, acc[2][2]);
            acc[2][3] = fmaf(xv.z, wv.w, acc[2][3]);
            acc[3][0] = fmaf(xv.w, wv.x, acc[3][0]);
            acc[3][1] = fmaf(xv.w, wv.y, acc[3][1]);
            acc[3][2] = fmaf(xv.w, wv.z, acc[3][2]);
            acc[3][3] = fmaf(xv.w, wv.w, acc[3][3]);
        }
    }

    #pragma unroll
    for (int i = 0; i < 4; ++i) {
        int row = r0 + tr * 4 + i;
        if (row < M) {
            float s = SCALE ? dis[row] : 1.0f;
            float4 st = make_float4(acc[i][0] * s, acc[i][1] * s, acc[i][2] * s, acc[i][3] * s);
            *(float4*)(Y + (size_t)row * 64 + tc * 4) = st;
        }
    }
}

// ---------------- pull aggregate ----------------
__global__ void pull_kernel(const float* __restrict__ hpre, const int* __restrict__ rowptr,
                            const int* __restrict__ srcs, const float* __restrict__ dis,
                            const float* __restrict__ b, float* __restrict__ out, int N) {
    int tid = threadIdx.x;
    int node = blockIdx.x * 4 + (tid >> 6);
    if (node >= N) return;
    int lane = tid & 63;
    float acc = hpre[(size_t)node * 64 + lane];  // self loop
    int i = rowptr[node], end = rowptr[node + 1];
    for (; i + 4 <= end; i += 4) {
        int s0 = srcs[i], s1 = srcs[i + 1], s2 = srcs[i + 2], s3 = srcs[i + 3];
        float v0 = hpre[(size_t)s0 * 64 + lane];
        float v1 = hpre[(size_t)s1 * 64 + lane];
        float v2 = hpre[(size_t)s2 * 64 + lane];
        float v3 = hpre[(size_t)s3 * 64 + lane];
        acc += v0 + v1 + v2 + v3;
    }
    for (; i < end; ++i) acc += hpre[(size_t)srcs[i] * 64 + lane];
    float o = acc * dis[node] + b[lane];
    out[(size_t)node * 64 + lane] = o > 0.f ? o : 0.f;
}

// ---------------- head ----------------
__global__ void head_kernel(const float* __restrict__ h, const int* __restrict__ pairs,
                            const float* __restrict__ Wh, const float* __restrict__ bh,
                            float* __restrict__ out, int P) {
    long long idx = (long long)blockIdx.x * blockDim.x + threadIdx.x;
    int p = (int)(idx >> 6);
    int lane = threadIdx.x & 63;
    if (p >= P) return;
    int p0 = pairs[2 * (size_t)p];
    int p1 = pairs[2 * (size_t)p + 1];
    float v = h[(size_t)p0 * 64 + lane] * Wh[lane]
            + h[(size_t)p1 * 64 + lane] * Wh[64 + lane];
    #pragma unroll
    for (int off = 32; off > 0; off >>= 1) v += __shfl_down(v, off);
    if (lane == 0) out[p] = v + bh[0];
}

// ---------------- fallback (atomic push) ----------------
__global__ void degf_kernel(const int* __restrict__ dst, float* __restrict__ deg, int E) {
    int e = blockIdx.x * blockDim.x + threadIdx.x;
    if (e < E) atomicAdd(&deg[dst[e]], 1.0f);
}
__global__ void rsqrtf_kernel(float* deg, int N) {
    int i = blockIdx.x * blockDim.x + threadIdx.x;
    if (i < N) deg[i] = rsqrtf(deg[i] + 1.0f);
}
__global__ void scatter_kernel(const float* __restrict__ h, const int* __restrict__ src,
                               const int* __restrict__ dst, const float* __restrict__ dis,
                               float* __restrict__ agg, int E, int N) {
    long long idx = (long long)blockIdx.x * blockDim.x + threadIdx.x;
    int e = (int)(idx >> 6);
    int f = (int)(idx & 63);
    if (e >= E + N) return;
    int s, d;
    if (e < E) { s = src[e]; d = dst[e]; } else { s = e - E; d = s; }
    float norm = dis[s] * dis[d];
    atomicAdd(&agg[(size_t)d * 64 + f], h[(size_t)s * 64 + f] * norm);
}
__global__ void bias_relu_kernel(float* __restrict__ buf, const float* __restrict__ b,
                                 long long total) {
    long long i = (long long)blockIdx.x * blockDim.x + threadIdx.x;
    if (i < total) {
        float v = buf[i] + b[(int)(i & 63)];
        buf[i] = v > 0.f ? v : 0.f;
    }
}

extern "C" void kernel_launch(void* const* d_in, const int* in_sizes, int n_in,
                              void* d_out, int out_size, void* d_ws, size_t ws_size,
                              hipStream_t stream) {
    const float* x     = (const float*)d_in[0];
    const int*   ei    = (const int*)d_in[1];   // [2,E]: row0=src, row1=dst
    const int*   pairs = (const int*)d_in[3];   // [P,2]
    const float* W1    = (const float*)d_in[4];
    const float* b1    = (const float*)d_in[5];
    const float* W2    = (const float*)d_in[6];
    const float* b2    = (const float*)d_in[7];
    const float* Wh    = (const float*)d_in[8];
    const float* bh    = (const float*)d_in[9];

    const int N = in_sizes[0] / 128;
    const int E = in_sizes[1] / 2;
    const int P = in_sizes[3] / 2;
    const int* srcArr = ei;
    const int* dstArr = ei + E;

    const size_t feat_total = (size_t)N * 64;
    const int NB = (N + BNODES - 1) / BNODES;      // dst buckets
    const int tileBlocks = (E + TILE - 1) / TILE;  // edge tiles
    const int gemm_blocks = (N + 63) / 64;

    auto align512 = [](size_t v) { return (v + 511) & ~(size_t)511; };

    char* ws = (char*)d_ws;
    size_t off = 0;
    float* dis    = (float*)(ws + off); off += align512((size_t)N * 4);
    int*   rowptr = (int*)  (ws + off); off += align512(((size_t)N + 1) * 4);
    int*   subcnt = (int*)  (ws + off); off += align512((size_t)NB * 4);
    int*   subcur = (int*)  (ws + off); off += align512((size_t)NB * 4);
    int*   subptr = (int*)  (ws + off); off += align512(((size_t)NB + 1) * 4);
    int*   srcs   = (int*)  (ws + off); off += align512((size_t)E * 4);
    float* bufA   = (float*)(ws + off); off += align512(feat_total * 4);
    float* bufB   = (float*)(ws + off); off += align512(feat_total * 4);
    int*   ebuf   = (int*)bufA;  // aliased: consumed by bin_fill before gemm1 writes bufA
    const bool csr_ok = (off <= ws_size) && (NB <= 1024) &&
                        (N <= (1 << PACK_SHIFT)) && ((size_t)E * 4 <= feat_total * 4);

    if (csr_ok) {
        // ---- CSR build ----
        hipMemsetAsync(subcnt, 0, (size_t)NB * 4, stream);
        hipMemsetAsync(subcur, 0, (size_t)NB * 4, stream);
        count_buckets<<<tileBlocks, 256, 0, stream>>>(dstArr, subcnt, NB, E);
        scan_small_kernel<<<1, 1024, 0, stream>>>(subcnt, subptr, NB, E);
        block_scatter<<<tileBlocks, 256, 0, stream>>>(srcArr, dstArr, subptr, subcur,
                                                      ebuf, NB, E);
        bin_fill_kernel<<<NB, 256, 0, stream>>>(ebuf, subptr, rowptr, dis, srcs, NB, N, E);

        // ---- layer 1 ----
        gemm_tiled<128, true><<<gemm_blocks, THREADS, 0, stream>>>(x, W1, dis, bufA, N);
        pull_kernel<<<(N + 3) / 4, THREADS, 0, stream>>>(bufA, rowptr, srcs, dis, b1, bufB, N);

        // ---- layer 2 ----
        gemm_tiled<64, true><<<gemm_blocks, THREADS, 0, stream>>>(bufB, W2, dis, bufA, N);
        pull_kernel<<<(N + 3) / 4, THREADS, 0, stream>>>(bufA, rowptr, srcs, dis, b2, bufB, N);

        // ---- head ----
        head_kernel<<<(unsigned)(((size_t)P * 64 + THREADS - 1) / THREADS), THREADS, 0, stream>>>(
            bufB, pairs, Wh, bh, (float*)d_out, P);
    } else {
        // ---- fallback: atomic push path ----
        size_t o2 = 0;
        float* deg  = (float*)(ws + o2); o2 += align512((size_t)N * 4);
        float* bA   = (float*)(ws + o2); o2 += align512(feat_total * 4);
        float* bB   = (float*)(ws + o2);
        const size_t edge_threads = (size_t)(E + N) * 64;
        const int eblocks = (E + THREADS - 1) / THREADS;

        hipMemsetAsync(deg, 0, (size_t)N * 4, stream);
        degf_kernel<<<eblocks, THREADS, 0, stream>>>(dstArr, deg, E);
        rsqrtf_kernel<<<(N + THREADS - 1) / THREADS, THREADS, 0, stream>>>(deg, N);

        gemm_tiled<128, false><<<gemm_blocks, THREADS, 0, stream>>>(x, W1, deg, bA, N);
        hipMemsetAsync(bB, 0, feat_total * 4, stream);
        scatter_kernel<<<(unsigned)((edge_threads + THREADS - 1) / THREADS), THREADS, 0, stream>>>(
            bA, srcArr, dstArr, deg, bB, E, N);
        bias_relu_kernel<<<(unsigned)((feat_total + THREADS - 1) / THREADS), THREADS, 0, stream>>>(
            bB, b1, (long long)feat_total);

        gemm_tiled<64, false><<<gemm_blocks, THREADS, 0, stream>>>(bB, W2, deg, bA, N);
        hipMemsetAsync(bB, 0, feat_total * 4, stream);
        scatter_kernel<<<(unsigned)((edge_threads + THREADS - 1) / THREADS), THREADS, 0, stream>>>(
            bA, srcArr, dstArr, deg, bB, E, N);
        bias_relu_kernel<<<(unsigned)((feat_total + THREADS - 1) / THREADS), THREADS, 0, stream>>>(
            bB, b2, (long long)feat_total);

        head_kernel<<<(unsigned)(((size_t)P * 64 + THREADS - 1) / THREADS), THREADS, 0, stream>>>(
            bB, pairs, Wh, bh, (float*)d_out, P);
    }
}

// Round 6
// 304.031 us; speedup vs baseline: 1.9378x; 1.1906x over previous
//
#include <hip/hip_runtime.h>

#define THREADS 256
#define BNODES 256           // nodes per dst-bucket
#define PACK_SHIFT 20        // src in low 20 bits, local dst in bits 20..27
#define TILE 8192            // edges per block in count/scatter

// ---------------- CSR build: block-binned counting sort, no per-edge global atomics ----

__global__ __launch_bounds__(256) void count_buckets(const int* __restrict__ dst,
                                                     int* __restrict__ subcnt,
                                                     int NB, int E) {
    __shared__ int h[1024];
    int t = threadIdx.x;
    for (int i = t; i < NB; i += 256) h[i] = 0;
    __syncthreads();
    int e0 = blockIdx.x * TILE;
    int e1 = min(e0 + TILE, E);
    for (int e = e0 + t; e < e1; e += 256)
        atomicAdd(&h[dst[e] >> 8], 1);
    __syncthreads();
    for (int i = t; i < NB; i += 256)
        if (h[i] > 0) atomicAdd(&subcnt[i], h[i]);
}

__global__ void scan_small_kernel(const int* __restrict__ cnt, int* __restrict__ ptr,
                                  int nb, int total) {
    __shared__ int sh[1024];
    int t = threadIdx.x;
    int v = (t < nb) ? cnt[t] : 0;
    sh[t] = v;
    __syncthreads();
    for (int off = 1; off < 1024; off <<= 1) {
        int add = (t >= off) ? sh[t - off] : 0;
        __syncthreads();
        sh[t] += add;
        __syncthreads();
    }
    if (t < nb) ptr[t] = sh[t] - v;
    if (t == 0) ptr[nb] = total;
}

__global__ __launch_bounds__(256) void block_scatter(const int* __restrict__ src,
                                                     const int* __restrict__ dst,
                                                     const int* __restrict__ subptr,
                                                     int* __restrict__ subcur,
                                                     int* __restrict__ ebuf,
                                                     int NB, int E) {
    __shared__ int h[1024];
    __shared__ int bb[1024];
    int t = threadIdx.x;
    for (int i = t; i < NB; i += 256) h[i] = 0;
    __syncthreads();
    int e0 = blockIdx.x * TILE;
    int e1 = min(e0 + TILE, E);
    for (int e = e0 + t; e < e1; e += 256)
        atomicAdd(&h[dst[e] >> 8], 1);
    __syncthreads();
    for (int i = t; i < NB; i += 256) {
        int c = h[i];
        bb[i] = (c > 0) ? (subptr[i] + atomicAdd(&subcur[i], c)) : 0;
        h[i] = 0;  // reuse as cursor
    }
    __syncthreads();
    for (int e = e0 + t; e < e1; e += 256) {
        int d = dst[e];
        int b = d >> 8;
        int pos = bb[b] + atomicAdd(&h[b], 1);
        ebuf[pos] = src[e] | ((d & (BNODES - 1)) << PACK_SHIFT);
    }
}

__global__ __launch_bounds__(256) void bin_fill_kernel(const int* __restrict__ ebuf,
                                                       const int* __restrict__ subptr,
                                                       int* __restrict__ rowptr,
                                                       float* __restrict__ dis,
                                                       int* __restrict__ srcs,
                                                       int NB, int N, int E) {
    __shared__ int cntL[BNODES];
    __shared__ int rb[BNODES];
    int b = blockIdx.x;
    int t = threadIdx.x;
    int base = b * BNODES;
    int s0 = subptr[b], s1 = subptr[b + 1];
    cntL[t] = 0;
    __syncthreads();
    for (int i = s0 + t; i < s1; i += 256)
        atomicAdd(&cntL[((unsigned)ebuf[i]) >> PACK_SHIFT], 1);
    __syncthreads();
    int myc = cntL[t];
    if (base + t < N) dis[base + t] = rsqrtf((float)myc + 1.0f);
    rb[t] = myc;
    __syncthreads();
    #pragma unroll
    for (int off = 1; off < 256; off <<= 1) {
        int add = (t >= off) ? rb[t - off] : 0;
        __syncthreads();
        rb[t] += add;
        __syncthreads();
    }
    int excl = rb[t] - myc;
    rb[t] = s0 + excl;
    if (base + t < N) rowptr[base + t] = s0 + excl;
    if (b == NB - 1 && t == 0) rowptr[N] = E;
    cntL[t] = 0;  // reuse as cursor
    __syncthreads();
    const int mask = (1 << PACK_SHIFT) - 1;
    for (int i = s0 + t; i < s1; i += 256) {
        int w = ebuf[i];
        int local = ((unsigned)w) >> PACK_SHIFT;
        int pos = rb[local] + atomicAdd(&cntL[local], 1);
        srcs[pos] = w & mask;
    }
}

// ---------------- tiled GEMM ----------------
template<int K, bool SCALE>
__global__ __launch_bounds__(256) void gemm_tiled(const float* __restrict__ X,
                                                  const float* __restrict__ W,
                                                  const float* __restrict__ dis,
                                                  float* __restrict__ Y, int M) {
    __shared__ float Ws[K * 64];
    __shared__ float Xs[32 * 68];
    const int t = threadIdx.x;

    for (int i = t; i < K * 16; i += THREADS)
        ((float4*)Ws)[i] = ((const float4*)W)[i];

    const int r0 = blockIdx.x * 64;
    const int wave = t >> 6;
    const int lane = t & 63;
    const int tr = lane & 15;
    const int tc = (lane >> 4) + wave * 4;

    float acc[4][4] = {};

    for (int kc = 0; kc < K; kc += 32) {
        __syncthreads();
        #pragma unroll
        for (int i = t; i < 512; i += THREADS) {
            int row = i >> 3;
            int kq = i & 7;
            int gr = r0 + row;
            if (gr >= M) gr = M - 1;
            float4 v = *(const float4*)(X + (size_t)gr * K + kc + kq * 4);
            Xs[(kq * 4 + 0) * 68 + row] = v.x;
            Xs[(kq * 4 + 1) * 68 + row] = v.y;
            Xs[(kq * 4 + 2) * 68 + row] = v.z;
            Xs[(kq * 4 + 3) * 68 + row] = v.w;
        }
        __syncthreads();
        #pragma unroll
        for (int kk = 0; kk < 32; ++kk) {
            float4 xv = *(const float4*)(Xs + kk * 68 + tr * 4);
            float4 wv = *(const float4*)(Ws + (kc + kk) * 64 + tc * 4);
            acc[0][0] = fmaf(xv.x, wv.x, acc[0][0]);
            acc[0][1] = fmaf(xv.x, wv.y, acc[0][1]);
            acc[0][2] = fmaf(xv.x, wv.z, acc[0][2]);
            acc[0][3] = fmaf(xv.x, wv.w, acc[0][3]);
            acc[1][0] = fmaf(xv.y, wv.x, acc[1][0]);
            acc[1][1] = fmaf(xv.y, wv.y, acc[1][1]);
            acc[1][2] = fmaf(xv.y, wv.z, acc[1][2]);
            acc[1][3] = fmaf(xv.y, wv.w, acc[1][3]);
            acc[2][0] = fmaf(xv.z, wv.x, acc[2][0]);
            acc[2][1] = fmaf(xv.z, wv.y, acc[2][1]);
            acc[2][2] = fmaf(xv.z, wv.z, acc[2][2]);
            acc[2][3] = fmaf(xv.z, wv.w, acc[2][3]);
            acc[3][0] = fmaf(xv.w, wv.x, acc[3][0]);
            acc[3][1] = fmaf(xv.w, wv.y, acc[3][1]);
            acc[3][2] = fmaf(xv.w, wv.z, acc[3][2]);
            acc[3][3] = fmaf(xv.w, wv.w, acc[3][3]);
        }
    }

    #pragma unroll
    for (int i = 0; i < 4; ++i) {
        int row = r0 + tr * 4 + i;
        if (row < M) {
            float s = SCALE ? dis[row] : 1.0f;
            float4 st = make_float4(acc[i][0] * s, acc[i][1] * s, acc[i][2] * s, acc[i][3] * s);
            *(float4*)(Y + (size_t)row * 64 + tc * 4) = st;
        }
    }
}

// ---------------- pull aggregate (layer 1: writes full h) ----------------
__global__ void pull_kernel(const float* __restrict__ hpre, const int* __restrict__ rowptr,
                            const int* __restrict__ srcs, const float* __restrict__ dis,
                            const float* __restrict__ b, float* __restrict__ out, int N) {
    int tid = threadIdx.x;
    int node = blockIdx.x * 4 + (tid >> 6);
    if (node >= N) return;
    int lane = tid & 63;
    float acc = hpre[(size_t)node * 64 + lane];  // self loop
    int i = rowptr[node], end = rowptr[node + 1];
    for (; i + 4 <= end; i += 4) {
        int s0 = srcs[i], s1 = srcs[i + 1], s2 = srcs[i + 2], s3 = srcs[i + 3];
        float v0 = hpre[(size_t)s0 * 64 + lane];
        float v1 = hpre[(size_t)s1 * 64 + lane];
        float v2 = hpre[(size_t)s2 * 64 + lane];
        float v3 = hpre[(size_t)s3 * 64 + lane];
        acc += v0 + v1 + v2 + v3;
    }
    for (; i < end; ++i) acc += hpre[(size_t)srcs[i] * 64 + lane];
    float o = acc * dis[node] + b[lane];
    out[(size_t)node * 64 + lane] = o > 0.f ? o : 0.f;
}

// ---------------- pull aggregate + head dot (layer 2: writes only s0,s1 per node) ----
// s01[n] = { dot(h2[n], Wh[0:64]), dot(h2[n], Wh[64:128]) }
__global__ void pull_head_kernel(const float* __restrict__ hpre, const int* __restrict__ rowptr,
                                 const int* __restrict__ srcs, const float* __restrict__ dis,
                                 const float* __restrict__ b, const float* __restrict__ Wh,
                                 float2* __restrict__ s01, int N) {
    int tid = threadIdx.x;
    int node = blockIdx.x * 4 + (tid >> 6);
    if (node >= N) return;
    int lane = tid & 63;
    float acc = hpre[(size_t)node * 64 + lane];  // self loop
    int i = rowptr[node], end = rowptr[node + 1];
    for (; i + 4 <= end; i += 4) {
        int s0 = srcs[i], s1 = srcs[i + 1], s2 = srcs[i + 2], s3 = srcs[i + 3];
        float v0 = hpre[(size_t)s0 * 64 + lane];
        float v1 = hpre[(size_t)s1 * 64 + lane];
        float v2 = hpre[(size_t)s2 * 64 + lane];
        float v3 = hpre[(size_t)s3 * 64 + lane];
        acc += v0 + v1 + v2 + v3;
    }
    for (; i < end; ++i) acc += hpre[(size_t)srcs[i] * 64 + lane];
    float o = acc * dis[node] + b[lane];
    o = o > 0.f ? o : 0.f;
    float p0 = o * Wh[lane];
    float p1 = o * Wh[64 + lane];
    #pragma unroll
    for (int off = 32; off > 0; off >>= 1) {
        p0 += __shfl_down(p0, off);
        p1 += __shfl_down(p1, off);
    }
    if (lane == 0) s01[node] = make_float2(p0, p1);
}

// out[p] = s01[p0].x + s01[p1].y + bh  (s01 is ~800KB -> L2-resident gathers)
__global__ void pair_kernel(const float2* __restrict__ s01, const int* __restrict__ pairs,
                            const float* __restrict__ bh, float* __restrict__ out, int P) {
    int p = blockIdx.x * blockDim.x + threadIdx.x;
    if (p < P) {
        int p0 = pairs[2 * (size_t)p];
        int p1 = pairs[2 * (size_t)p + 1];
        out[p] = s01[p0].x + s01[p1].y + bh[0];
    }
}

// ---------------- fallback (atomic push) ----------------
__global__ void degf_kernel(const int* __restrict__ dst, float* __restrict__ deg, int E) {
    int e = blockIdx.x * blockDim.x + threadIdx.x;
    if (e < E) atomicAdd(&deg[dst[e]], 1.0f);
}
__global__ void rsqrtf_kernel(float* deg, int N) {
    int i = blockIdx.x * blockDim.x + threadIdx.x;
    if (i < N) deg[i] = rsqrtf(deg[i] + 1.0f);
}
__global__ void scatter_kernel(const float* __restrict__ h, const int* __restrict__ src,
                               const int* __restrict__ dst, const float* __restrict__ dis,
                               float* __restrict__ agg, int E, int N) {
    long long idx = (long long)blockIdx.x * blockDim.x + threadIdx.x;
    int e = (int)(idx >> 6);
    int f = (int)(idx & 63);
    if (e >= E + N) return;
    int s, d;
    if (e < E) { s = src[e]; d = dst[e]; } else { s = e - E; d = s; }
    float norm = dis[s] * dis[d];
    atomicAdd(&agg[(size_t)d * 64 + f], h[(size_t)s * 64 + f] * norm);
}
__global__ void bias_relu_kernel(float* __restrict__ buf, const float* __restrict__ b,
                                 long long total) {
    long long i = (long long)blockIdx.x * blockDim.x + threadIdx.x;
    if (i < total) {
        float v = buf[i] + b[(int)(i & 63)];
        buf[i] = v > 0.f ? v : 0.f;
    }
}
__global__ void head_kernel(const float* __restrict__ h, const int* __restrict__ pairs,
                            const float* __restrict__ Wh, const float* __restrict__ bh,
                            float* __restrict__ out, int P) {
    long long idx = (long long)blockIdx.x * blockDim.x + threadIdx.x;
    int p = (int)(idx >> 6);
    int lane = threadIdx.x & 63;
    if (p >= P) return;
    int p0 = pairs[2 * (size_t)p];
    int p1 = pairs[2 * (size_t)p + 1];
    float v = h[(size_t)p0 * 64 + lane] * Wh[lane]
            + h[(size_t)p1 * 64 + lane] * Wh[64 + lane];
    #pragma unroll
    for (int off = 32; off > 0; off >>= 1) v += __shfl_down(v, off);
    if (lane == 0) out[p] = v + bh[0];
}

extern "C" void kernel_launch(void* const* d_in, const int* in_sizes, int n_in,
                              void* d_out, int out_size, void* d_ws, size_t ws_size,
                              hipStream_t stream) {
    const float* x     = (const float*)d_in[0];
    const int*   ei    = (const int*)d_in[1];   // [2,E]: row0=src, row1=dst
    const int*   pairs = (const int*)d_in[3];   // [P,2]
    const float* W1    = (const float*)d_in[4];
    const float* b1    = (const float*)d_in[5];
    const float* W2    = (const float*)d_in[6];
    const float* b2    = (const float*)d_in[7];
    const float* Wh    = (const float*)d_in[8];
    const float* bh    = (const float*)d_in[9];

    const int N = in_sizes[0] / 128;
    const int E = in_sizes[1] / 2;
    const int P = in_sizes[3] / 2;
    const int* srcArr = ei;
    const int* dstArr = ei + E;

    const size_t feat_total = (size_t)N * 64;
    const int NB = (N + BNODES - 1) / BNODES;      // dst buckets
    const int tileBlocks = (E + TILE - 1) / TILE;  // edge tiles
    const int gemm_blocks = (N + 63) / 64;

    auto align512 = [](size_t v) { return (v + 511) & ~(size_t)511; };

    char* ws = (char*)d_ws;
    size_t off = 0;
    float*  dis    = (float*) (ws + off); off += align512((size_t)N * 4);
    int*    rowptr = (int*)   (ws + off); off += align512(((size_t)N + 1) * 4);
    int*    subcnt = (int*)   (ws + off); off += align512((size_t)NB * 4);
    int*    subcur = (int*)   (ws + off); off += align512((size_t)NB * 4);
    int*    subptr = (int*)   (ws + off); off += align512(((size_t)NB + 1) * 4);
    float2* s01    = (float2*)(ws + off); off += align512((size_t)N * 8);
    int*    srcs   = (int*)   (ws + off); off += align512((size_t)E * 4);
    float*  bufA   = (float*) (ws + off); off += align512(feat_total * 4);
    float*  bufB   = (float*) (ws + off); off += align512(feat_total * 4);
    int*    ebuf   = (int*)bufA;  // aliased: consumed by bin_fill before gemm1 writes bufA
    const bool csr_ok = (off <= ws_size) && (NB <= 1024) &&
                        (N <= (1 << PACK_SHIFT)) && ((size_t)E * 4 <= feat_total * 4);

    if (csr_ok) {
        // ---- CSR build ----
        hipMemsetAsync(subcnt, 0, (size_t)NB * 4, stream);
        hipMemsetAsync(subcur, 0, (size_t)NB * 4, stream);
        count_buckets<<<tileBlocks, 256, 0, stream>>>(dstArr, subcnt, NB, E);
        scan_small_kernel<<<1, 1024, 0, stream>>>(subcnt, subptr, NB, E);
        block_scatter<<<tileBlocks, 256, 0, stream>>>(srcArr, dstArr, subptr, subcur,
                                                      ebuf, NB, E);
        bin_fill_kernel<<<NB, 256, 0, stream>>>(ebuf, subptr, rowptr, dis, srcs, NB, N, E);

        // ---- layer 1 ----
        gemm_tiled<128, true><<<gemm_blocks, THREADS, 0, stream>>>(x, W1, dis, bufA, N);
        pull_kernel<<<(N + 3) / 4, THREADS, 0, stream>>>(bufA, rowptr, srcs, dis, b1, bufB, N);

        // ---- layer 2 + head dots fused ----
        gemm_tiled<64, true><<<gemm_blocks, THREADS, 0, stream>>>(bufB, W2, dis, bufA, N);
        pull_head_kernel<<<(N + 3) / 4, THREADS, 0, stream>>>(bufA, rowptr, srcs, dis, b2,
                                                              Wh, s01, N);

        // ---- pair gather ----
        pair_kernel<<<(P + THREADS - 1) / THREADS, THREADS, 0, stream>>>(
            s01, pairs, bh, (float*)d_out, P);
    } else {
        // ---- fallback: atomic push path ----
        size_t o2 = 0;
        float* deg  = (float*)(ws + o2); o2 += align512((size_t)N * 4);
        float* bA   = (float*)(ws + o2); o2 += align512(feat_total * 4);
        float* bB   = (float*)(ws + o2);
        const size_t edge_threads = (size_t)(E + N) * 64;
        const int eblocks = (E + THREADS - 1) / THREADS;

        hipMemsetAsync(deg, 0, (size_t)N * 4, stream);
        degf_kernel<<<eblocks, THREADS, 0, stream>>>(dstArr, deg, E);
        rsqrtf_kernel<<<(N + THREADS - 1) / THREADS, THREADS, 0, stream>>>(deg, N);

        gemm_tiled<128, false><<<gemm_blocks, THREADS, 0, stream>>>(x, W1, deg, bA, N);
        hipMemsetAsync(bB, 0, feat_total * 4, stream);
        scatter_kernel<<<(unsigned)((edge_threads + THREADS - 1) / THREADS), THREADS, 0, stream>>>(
            bA, srcArr, dstArr, deg, bB, E, N);
        bias_relu_kernel<<<(unsigned)((feat_total + THREADS - 1) / THREADS), THREADS, 0, stream>>>(
            bB, b1, (long long)feat_total);

        gemm_tiled<64, false><<<gemm_blocks, THREADS, 0, stream>>>(bB, W2, deg, bA, N);
        hipMemsetAsync(bB, 0, feat_total * 4, stream);
        scatter_kernel<<<(unsigned)((edge_threads + THREADS - 1) / THREADS), THREADS, 0, stream>>>(
            bA, srcArr, dstArr, deg, bB, E, N);
        bias_relu_kernel<<<(unsigned)((feat_total + THREADS - 1) / THREADS), THREADS, 0, stream>>>(
            bB, b2, (long long)feat_total);

        head_kernel<<<(unsigned)(((size_t)P * 64 + THREADS - 1) / THREADS), THREADS, 0, stream>>>(
            bB, pairs, Wh, bh, (float*)d_out, P);
    }
}

// Round 7
// 291.662 us; speedup vs baseline: 2.0199x; 1.0424x over previous
//
#include <hip/hip_runtime.h>

#define THREADS 256
#define BNODES 256           // nodes per dst-bucket
#define PACK_SHIFT 20        // src in low 20 bits, local dst in bits 20..27
#define TILE 8192            // edges per block in count/scatter

__device__ __forceinline__ unsigned short f2bf(float f) {
    unsigned u = __float_as_uint(f);
    unsigned r = (u + 0x7fff + ((u >> 16) & 1)) >> 16;  // RNE
    return (unsigned short)r;
}
__device__ __forceinline__ float bf2f(unsigned short s) {
    return __uint_as_float(((unsigned)s) << 16);
}

// ---------------- CSR build: block-binned counting sort, no per-edge global atomics ----

__global__ __launch_bounds__(256) void count_buckets(const int* __restrict__ dst,
                                                     int* __restrict__ subcnt,
                                                     int NB, int E) {
    __shared__ int h[1024];
    int t = threadIdx.x;
    for (int i = t; i < NB; i += 256) h[i] = 0;
    __syncthreads();
    int e0 = blockIdx.x * TILE;
    int e1 = min(e0 + TILE, E);
    for (int e = e0 + t; e < e1; e += 256)
        atomicAdd(&h[dst[e] >> 8], 1);
    __syncthreads();
    for (int i = t; i < NB; i += 256)
        if (h[i] > 0) atomicAdd(&subcnt[i], h[i]);
}

__global__ void scan_small_kernel(const int* __restrict__ cnt, int* __restrict__ ptr,
                                  int nb, int total) {
    __shared__ int sh[1024];
    int t = threadIdx.x;
    int v = (t < nb) ? cnt[t] : 0;
    sh[t] = v;
    __syncthreads();
    for (int off = 1; off < 1024; off <<= 1) {
        int add = (t >= off) ? sh[t - off] : 0;
        __syncthreads();
        sh[t] += add;
        __syncthreads();
    }
    if (t < nb) ptr[t] = sh[t] - v;
    if (t == 0) ptr[nb] = total;
}

__global__ __launch_bounds__(256) void block_scatter(const int* __restrict__ src,
                                                     const int* __restrict__ dst,
                                                     const int* __restrict__ subptr,
                                                     int* __restrict__ subcur,
                                                     int* __restrict__ ebuf,
                                                     int NB, int E) {
    __shared__ int h[1024];
    __shared__ int bb[1024];
    int t = threadIdx.x;
    for (int i = t; i < NB; i += 256) h[i] = 0;
    __syncthreads();
    int e0 = blockIdx.x * TILE;
    int e1 = min(e0 + TILE, E);
    for (int e = e0 + t; e < e1; e += 256)
        atomicAdd(&h[dst[e] >> 8], 1);
    __syncthreads();
    for (int i = t; i < NB; i += 256) {
        int c = h[i];
        bb[i] = (c > 0) ? (subptr[i] + atomicAdd(&subcur[i], c)) : 0;
        h[i] = 0;  // reuse as cursor
    }
    __syncthreads();
    for (int e = e0 + t; e < e1; e += 256) {
        int d = dst[e];
        int b = d >> 8;
        int pos = bb[b] + atomicAdd(&h[b], 1);
        ebuf[pos] = src[e] | ((d & (BNODES - 1)) << PACK_SHIFT);
    }
}

__global__ __launch_bounds__(256) void bin_fill_kernel(const int* __restrict__ ebuf,
                                                       const int* __restrict__ subptr,
                                                       int* __restrict__ rowptr,
                                                       float* __restrict__ dis,
                                                       int* __restrict__ srcs,
                                                       int NB, int N, int E) {
    __shared__ int cntL[BNODES];
    __shared__ int rb[BNODES];
    int b = blockIdx.x;
    int t = threadIdx.x;
    int base = b * BNODES;
    int s0 = subptr[b], s1 = subptr[b + 1];
    cntL[t] = 0;
    __syncthreads();
    for (int i = s0 + t; i < s1; i += 256)
        atomicAdd(&cntL[((unsigned)ebuf[i]) >> PACK_SHIFT], 1);
    __syncthreads();
    int myc = cntL[t];
    if (base + t < N) dis[base + t] = rsqrtf((float)myc + 1.0f);
    rb[t] = myc;
    __syncthreads();
    #pragma unroll
    for (int off = 1; off < 256; off <<= 1) {
        int add = (t >= off) ? rb[t - off] : 0;
        __syncthreads();
        rb[t] += add;
        __syncthreads();
    }
    int excl = rb[t] - myc;
    rb[t] = s0 + excl;
    if (base + t < N) rowptr[base + t] = s0 + excl;
    if (b == NB - 1 && t == 0) rowptr[N] = E;
    cntL[t] = 0;  // reuse as cursor
    __syncthreads();
    const int mask = (1 << PACK_SHIFT) - 1;
    for (int i = s0 + t; i < s1; i += 256) {
        int w = ebuf[i];
        int local = ((unsigned)w) >> PACK_SHIFT;
        int pos = rb[local] + atomicAdd(&cntL[local], 1);
        srcs[pos] = w & mask;
    }
}

// ---------------- tiled GEMM ----------------
// Y[M,64] = X[M,K] @ W[K,64], optional row-scale by dis[row].
// YT = unsigned short -> bf16 output (for gather-bound consumers); float -> fp32.
template<int K, bool SCALE, typename YT>
__global__ __launch_bounds__(256) void gemm_tiled(const float* __restrict__ X,
                                                  const float* __restrict__ W,
                                                  const float* __restrict__ dis,
                                                  YT* __restrict__ Y, int M) {
    __shared__ float Ws[K * 64];
    __shared__ float Xs[32 * 68];
    const int t = threadIdx.x;

    for (int i = t; i < K * 16; i += THREADS)
        ((float4*)Ws)[i] = ((const float4*)W)[i];

    const int r0 = blockIdx.x * 64;
    const int wave = t >> 6;
    const int lane = t & 63;
    const int tr = lane & 15;
    const int tc = (lane >> 4) + wave * 4;

    float acc[4][4] = {};

    for (int kc = 0; kc < K; kc += 32) {
        __syncthreads();
        #pragma unroll
        for (int i = t; i < 512; i += THREADS) {
            int row = i >> 3;
            int kq = i & 7;
            int gr = r0 + row;
            if (gr >= M) gr = M - 1;
            float4 v = *(const float4*)(X + (size_t)gr * K + kc + kq * 4);
            Xs[(kq * 4 + 0) * 68 + row] = v.x;
            Xs[(kq * 4 + 1) * 68 + row] = v.y;
            Xs[(kq * 4 + 2) * 68 + row] = v.z;
            Xs[(kq * 4 + 3) * 68 + row] = v.w;
        }
        __syncthreads();
        #pragma unroll
        for (int kk = 0; kk < 32; ++kk) {
            float4 xv = *(const float4*)(Xs + kk * 68 + tr * 4);
            float4 wv = *(const float4*)(Ws + (kc + kk) * 64 + tc * 4);
            acc[0][0] = fmaf(xv.x, wv.x, acc[0][0]);
            acc[0][1] = fmaf(xv.x, wv.y, acc[0][1]);
            acc[0][2] = fmaf(xv.x, wv.z, acc[0][2]);
            acc[0][3] = fmaf(xv.x, wv.w, acc[0][3]);
            acc[1][0] = fmaf(xv.y, wv.x, acc[1][0]);
            acc[1][1] = fmaf(xv.y, wv.y, acc[1][1]);
            acc[1][2] = fmaf(xv.y, wv.z, acc[1][2]);
            acc[1][3] = fmaf(xv.y, wv.w, acc[1][3]);
            acc[2][0] = fmaf(xv.z, wv.x, acc[2][0]);
            acc[2][1] = fmaf(xv.z, wv.y, acc[2][1]);
            acc[2][2] = fmaf(xv.z, wv.z, acc[2][2]);
            acc[2][3] = fmaf(xv.z, wv.w, acc[2][3]);
            acc[3][0] = fmaf(xv.w, wv.x, acc[3][0]);
            acc[3][1] = fmaf(xv.w, wv.y, acc[3][1]);
            acc[3][2] = fmaf(xv.w, wv.z, acc[3][2]);
            acc[3][3] = fmaf(xv.w, wv.w, acc[3][3]);
        }
    }

    #pragma unroll
    for (int i = 0; i < 4; ++i) {
        int row = r0 + tr * 4 + i;
        if (row < M) {
            float s = SCALE ? dis[row] : 1.0f;
            if constexpr (sizeof(YT) == 2) {
                ushort4 st;
                st.x = f2bf(acc[i][0] * s);
                st.y = f2bf(acc[i][1] * s);
                st.z = f2bf(acc[i][2] * s);
                st.w = f2bf(acc[i][3] * s);
                *(ushort4*)((unsigned short*)Y + (size_t)row * 64 + tc * 4) = st;
            } else {
                float4 st = make_float4(acc[i][0] * s, acc[i][1] * s,
                                        acc[i][2] * s, acc[i][3] * s);
                *(float4*)((float*)Y + (size_t)row * 64 + tc * 4) = st;
            }
        }
    }
}

// ---------------- pull aggregate (layer 1: bf16 gather in, fp32 h out) ----------------
__global__ void pull_kernel(const unsigned short* __restrict__ hpre,
                            const int* __restrict__ rowptr,
                            const int* __restrict__ srcs, const float* __restrict__ dis,
                            const float* __restrict__ b, float* __restrict__ out, int N) {
    int tid = threadIdx.x;
    int node = blockIdx.x * 4 + (tid >> 6);
    if (node >= N) return;
    int lane = tid & 63;
    float acc = bf2f(hpre[(size_t)node * 64 + lane]);  // self loop
    int i = rowptr[node], end = rowptr[node + 1];
    for (; i + 4 <= end; i += 4) {
        int s0 = srcs[i], s1 = srcs[i + 1], s2 = srcs[i + 2], s3 = srcs[i + 3];
        float v0 = bf2f(hpre[(size_t)s0 * 64 + lane]);
        float v1 = bf2f(hpre[(size_t)s1 * 64 + lane]);
        float v2 = bf2f(hpre[(size_t)s2 * 64 + lane]);
        float v3 = bf2f(hpre[(size_t)s3 * 64 + lane]);
        acc += v0 + v1 + v2 + v3;
    }
    for (; i < end; ++i) acc += bf2f(hpre[(size_t)srcs[i] * 64 + lane]);
    float o = acc * dis[node] + b[lane];
    out[(size_t)node * 64 + lane] = o > 0.f ? o : 0.f;
}

// ---------------- pull aggregate + head dot (layer 2, bf16 gather in) ----------------
__global__ void pull_head_kernel(const unsigned short* __restrict__ hpre,
                                 const int* __restrict__ rowptr,
                                 const int* __restrict__ srcs, const float* __restrict__ dis,
                                 const float* __restrict__ b, const float* __restrict__ Wh,
                                 float2* __restrict__ s01, int N) {
    int tid = threadIdx.x;
    int node = blockIdx.x * 4 + (tid >> 6);
    if (node >= N) return;
    int lane = tid & 63;
    float acc = bf2f(hpre[(size_t)node * 64 + lane]);  // self loop
    int i = rowptr[node], end = rowptr[node + 1];
    for (; i + 4 <= end; i += 4) {
        int s0 = srcs[i], s1 = srcs[i + 1], s2 = srcs[i + 2], s3 = srcs[i + 3];
        float v0 = bf2f(hpre[(size_t)s0 * 64 + lane]);
        float v1 = bf2f(hpre[(size_t)s1 * 64 + lane]);
        float v2 = bf2f(hpre[(size_t)s2 * 64 + lane]);
        float v3 = bf2f(hpre[(size_t)s3 * 64 + lane]);
        acc += v0 + v1 + v2 + v3;
    }
    for (; i < end; ++i) acc += bf2f(hpre[(size_t)srcs[i] * 64 + lane]);
    float o = acc * dis[node] + b[lane];
    o = o > 0.f ? o : 0.f;
    float p0 = o * Wh[lane];
    float p1 = o * Wh[64 + lane];
    #pragma unroll
    for (int off = 32; off > 0; off >>= 1) {
        p0 += __shfl_down(p0, off);
        p1 += __shfl_down(p1, off);
    }
    if (lane == 0) s01[node] = make_float2(p0, p1);
}

// out[p] = s01[p0].x + s01[p1].y + bh  (s01 is ~800KB -> L2-resident gathers)
__global__ void pair_kernel(const float2* __restrict__ s01, const int* __restrict__ pairs,
                            const float* __restrict__ bh, float* __restrict__ out, int P) {
    int p = blockIdx.x * blockDim.x + threadIdx.x;
    if (p < P) {
        int p0 = pairs[2 * (size_t)p];
        int p1 = pairs[2 * (size_t)p + 1];
        out[p] = s01[p0].x + s01[p1].y + bh[0];
    }
}

// ---------------- fallback (atomic push, full fp32) ----------------
__global__ void degf_kernel(const int* __restrict__ dst, float* __restrict__ deg, int E) {
    int e = blockIdx.x * blockDim.x + threadIdx.x;
    if (e < E) atomicAdd(&deg[dst[e]], 1.0f);
}
__global__ void rsqrtf_kernel(float* deg, int N) {
    int i = blockIdx.x * blockDim.x + threadIdx.x;
    if (i < N) deg[i] = rsqrtf(deg[i] + 1.0f);
}
__global__ void scatter_kernel(const float* __restrict__ h, const int* __restrict__ src,
                               const int* __restrict__ dst, const float* __restrict__ dis,
                               float* __restrict__ agg, int E, int N) {
    long long idx = (long long)blockIdx.x * blockDim.x + threadIdx.x;
    int e = (int)(idx >> 6);
    int f = (int)(idx & 63);
    if (e >= E + N) return;
    int s, d;
    if (e < E) { s = src[e]; d = dst[e]; } else { s = e - E; d = s; }
    float norm = dis[s] * dis[d];
    atomicAdd(&agg[(size_t)d * 64 + f], h[(size_t)s * 64 + f] * norm);
}
__global__ void bias_relu_kernel(float* __restrict__ buf, const float* __restrict__ b,
                                 long long total) {
    long long i = (long long)blockIdx.x * blockDim.x + threadIdx.x;
    if (i < total) {
        float v = buf[i] + b[(int)(i & 63)];
        buf[i] = v > 0.f ? v : 0.f;
    }
}
__global__ void head_kernel(const float* __restrict__ h, const int* __restrict__ pairs,
                            const float* __restrict__ Wh, const float* __restrict__ bh,
                            float* __restrict__ out, int P) {
    long long idx = (long long)blockIdx.x * blockDim.x + threadIdx.x;
    int p = (int)(idx >> 6);
    int lane = threadIdx.x & 63;
    if (p >= P) return;
    int p0 = pairs[2 * (size_t)p];
    int p1 = pairs[2 * (size_t)p + 1];
    float v = h[(size_t)p0 * 64 + lane] * Wh[lane]
            + h[(size_t)p1 * 64 + lane] * Wh[64 + lane];
    #pragma unroll
    for (int off = 32; off > 0; off >>= 1) v += __shfl_down(v, off);
    if (lane == 0) out[p] = v + bh[0];
}

extern "C" void kernel_launch(void* const* d_in, const int* in_sizes, int n_in,
                              void* d_out, int out_size, void* d_ws, size_t ws_size,
                              hipStream_t stream) {
    const float* x     = (const float*)d_in[0];
    const int*   ei    = (const int*)d_in[1];   // [2,E]: row0=src, row1=dst
    const int*   pairs = (const int*)d_in[3];   // [P,2]
    const float* W1    = (const float*)d_in[4];
    const float* b1    = (const float*)d_in[5];
    const float* W2    = (const float*)d_in[6];
    const float* b2    = (const float*)d_in[7];
    const float* Wh    = (const float*)d_in[8];
    const float* bh    = (const float*)d_in[9];

    const int N = in_sizes[0] / 128;
    const int E = in_sizes[1] / 2;
    const int P = in_sizes[3] / 2;
    const int* srcArr = ei;
    const int* dstArr = ei + E;

    const size_t feat_total = (size_t)N * 64;
    const int NB = (N + BNODES - 1) / BNODES;      // dst buckets
    const int tileBlocks = (E + TILE - 1) / TILE;  // edge tiles
    const int gemm_blocks = (N + 63) / 64;

    auto align512 = [](size_t v) { return (v + 511) & ~(size_t)511; };

    char* ws = (char*)d_ws;
    size_t off = 0;
    float*  dis    = (float*) (ws + off); off += align512((size_t)N * 4);
    int*    rowptr = (int*)   (ws + off); off += align512(((size_t)N + 1) * 4);
    int*    subcnt = (int*)   (ws + off); off += align512((size_t)NB * 4);
    int*    subcur = (int*)   (ws + off); off += align512((size_t)NB * 4);
    int*    subptr = (int*)   (ws + off); off += align512(((size_t)NB + 1) * 4);
    float2* s01    = (float2*)(ws + off); off += align512((size_t)N * 8);
    int*    srcs   = (int*)   (ws + off); off += align512((size_t)E * 4);
    // bufA slot holds: ebuf (E ints) early, then bf16 hpre [N][64]; sized for max.
    size_t bufA_bytes = align512((size_t)E * 4 > feat_total * 2 ? (size_t)E * 4
                                                                : feat_total * 2);
    unsigned short* bufA = (unsigned short*)(ws + off); off += bufA_bytes;
    float*  bufB   = (float*) (ws + off); off += align512(feat_total * 4);
    int*    ebuf   = (int*)bufA;  // aliased: consumed by bin_fill before gemm1 writes bufA
    const bool csr_ok = (off <= ws_size) && (NB <= 1024) && (N <= (1 << PACK_SHIFT));

    if (csr_ok) {
        // ---- CSR build ----
        hipMemsetAsync(subcnt, 0, (size_t)NB * 4, stream);
        hipMemsetAsync(subcur, 0, (size_t)NB * 4, stream);
        count_buckets<<<tileBlocks, 256, 0, stream>>>(dstArr, subcnt, NB, E);
        scan_small_kernel<<<1, 1024, 0, stream>>>(subcnt, subptr, NB, E);
        block_scatter<<<tileBlocks, 256, 0, stream>>>(srcArr, dstArr, subptr, subcur,
                                                      ebuf, NB, E);
        bin_fill_kernel<<<NB, 256, 0, stream>>>(ebuf, subptr, rowptr, dis, srcs, NB, N, E);

        // ---- layer 1: hpre(bf16) = (x@W1)*dis ; bufB(fp32) = relu(...) ----
        gemm_tiled<128, true, unsigned short><<<gemm_blocks, THREADS, 0, stream>>>(
            x, W1, dis, bufA, N);
        pull_kernel<<<(N + 3) / 4, THREADS, 0, stream>>>(bufA, rowptr, srcs, dis, b1, bufB, N);

        // ---- layer 2 + head dots fused ----
        gemm_tiled<64, true, unsigned short><<<gemm_blocks, THREADS, 0, stream>>>(
            bufB, W2, dis, bufA, N);
        pull_head_kernel<<<(N + 3) / 4, THREADS, 0, stream>>>(bufA, rowptr, srcs, dis, b2,
                                                              Wh, s01, N);

        // ---- pair gather ----
        pair_kernel<<<(P + THREADS - 1) / THREADS, THREADS, 0, stream>>>(
            s01, pairs, bh, (float*)d_out, P);
    } else {
        // ---- fallback: atomic push path, fp32 ----
        size_t o2 = 0;
        float* deg  = (float*)(ws + o2); o2 += align512((size_t)N * 4);
        float* bA   = (float*)(ws + o2); o2 += align512(feat_total * 4);
        float* bB   = (float*)(ws + o2);
        const size_t edge_threads = (size_t)(E + N) * 64;
        const int eblocks = (E + THREADS - 1) / THREADS;

        hipMemsetAsync(deg, 0, (size_t)N * 4, stream);
        degf_kernel<<<eblocks, THREADS, 0, stream>>>(dstArr, deg, E);
        rsqrtf_kernel<<<(N + THREADS - 1) / THREADS, THREADS, 0, stream>>>(deg, N);

        gemm_tiled<128, false, float><<<gemm_blocks, THREADS, 0, stream>>>(x, W1, deg, bA, N);
        hipMemsetAsync(bB, 0, feat_total * 4, stream);
        scatter_kernel<<<(unsigned)((edge_threads + THREADS - 1) / THREADS), THREADS, 0, stream>>>(
            bA, srcArr, dstArr, deg, bB, E, N);
        bias_relu_kernel<<<(unsigned)((feat_total + THREADS - 1) / THREADS), THREADS, 0, stream>>>(
            bB, b1, (long long)feat_total);

        gemm_tiled<64, false, float><<<gemm_blocks, THREADS, 0, stream>>>(bB, W2, deg, bA, N);
        hipMemsetAsync(bB, 0, feat_total * 4, stream);
        scatter_kernel<<<(unsigned)((edge_threads + THREADS - 1) / THREADS), THREADS, 0, stream>>>(
            bA, srcArr, dstArr, deg, bB, E, N);
        bias_relu_kernel<<<(unsigned)((feat_total + THREADS - 1) / THREADS), THREADS, 0, stream>>>(
            bB, b2, (long long)feat_total);

        head_kernel<<<(unsigned)(((size_t)P * 64 + THREADS - 1) / THREADS), THREADS, 0, stream>>>(
            bB, pairs, Wh, bh, (float*)d_out, P);
    }
}

// Round 8
// 235.292 us; speedup vs baseline: 2.5039x; 1.2396x over previous
//
#include <hip/hip_runtime.h>

#define THREADS 256
#define BNODES 256           // nodes per dst-bucket
#define PACK_SHIFT 20        // src in low 20 bits, local dst in bits 20..27
#define TILE 8192            // edges per block in count/scatter

__device__ __forceinline__ unsigned short f2bf(float f) {
    unsigned u = __float_as_uint(f);
    unsigned r = (u + 0x7fff + ((u >> 16) & 1)) >> 16;  // RNE
    return (unsigned short)r;
}
__device__ __forceinline__ float bf2f_lo(unsigned v) { return __uint_as_float(v << 16); }
__device__ __forceinline__ float bf2f_hi(unsigned v) { return __uint_as_float(v & 0xffff0000u); }

// ---------------- CSR build: block-binned counting sort, no per-edge global atomics ----

__global__ __launch_bounds__(256) void count_buckets(const int* __restrict__ dst,
                                                     int* __restrict__ subcnt,
                                                     int NB, int E) {
    __shared__ int h[1024];
    int t = threadIdx.x;
    for (int i = t; i < NB; i += 256) h[i] = 0;
    __syncthreads();
    int e0 = blockIdx.x * TILE;
    int e1 = min(e0 + TILE, E);
    for (int e = e0 + t; e < e1; e += 256)
        atomicAdd(&h[dst[e] >> 8], 1);
    __syncthreads();
    for (int i = t; i < NB; i += 256)
        if (h[i] > 0) atomicAdd(&subcnt[i], h[i]);
}

__global__ void scan_small_kernel(const int* __restrict__ cnt, int* __restrict__ ptr,
                                  int nb, int total) {
    __shared__ int sh[1024];
    int t = threadIdx.x;
    int v = (t < nb) ? cnt[t] : 0;
    sh[t] = v;
    __syncthreads();
    for (int off = 1; off < 1024; off <<= 1) {
        int add = (t >= off) ? sh[t - off] : 0;
        __syncthreads();
        sh[t] += add;
        __syncthreads();
    }
    if (t < nb) ptr[t] = sh[t] - v;
    if (t == 0) ptr[nb] = total;
}

__global__ __launch_bounds__(256) void block_scatter(const int* __restrict__ src,
                                                     const int* __restrict__ dst,
                                                     const int* __restrict__ subptr,
                                                     int* __restrict__ subcur,
                                                     int* __restrict__ ebuf,
                                                     int NB, int E) {
    __shared__ int h[1024];
    __shared__ int bb[1024];
    int t = threadIdx.x;
    for (int i = t; i < NB; i += 256) h[i] = 0;
    __syncthreads();
    int e0 = blockIdx.x * TILE;
    int e1 = min(e0 + TILE, E);
    for (int e = e0 + t; e < e1; e += 256)
        atomicAdd(&h[dst[e] >> 8], 1);
    __syncthreads();
    for (int i = t; i < NB; i += 256) {
        int c = h[i];
        bb[i] = (c > 0) ? (subptr[i] + atomicAdd(&subcur[i], c)) : 0;
        h[i] = 0;  // reuse as cursor
    }
    __syncthreads();
    for (int e = e0 + t; e < e1; e += 256) {
        int d = dst[e];
        int b = d >> 8;
        int pos = bb[b] + atomicAdd(&h[b], 1);
        ebuf[pos] = src[e] | ((d & (BNODES - 1)) << PACK_SHIFT);
    }
}

__global__ __launch_bounds__(256) void bin_fill_kernel(const int* __restrict__ ebuf,
                                                       const int* __restrict__ subptr,
                                                       int* __restrict__ rowptr,
                                                       float* __restrict__ dis,
                                                       int* __restrict__ srcs,
                                                       int NB, int N, int E) {
    __shared__ int cntL[BNODES];
    __shared__ int rb[BNODES];
    int b = blockIdx.x;
    int t = threadIdx.x;
    int base = b * BNODES;
    int s0 = subptr[b], s1 = subptr[b + 1];
    cntL[t] = 0;
    __syncthreads();
    for (int i = s0 + t; i < s1; i += 256)
        atomicAdd(&cntL[((unsigned)ebuf[i]) >> PACK_SHIFT], 1);
    __syncthreads();
    int myc = cntL[t];
    if (base + t < N) dis[base + t] = rsqrtf((float)myc + 1.0f);
    rb[t] = myc;
    __syncthreads();
    #pragma unroll
    for (int off = 1; off < 256; off <<= 1) {
        int add = (t >= off) ? rb[t - off] : 0;
        __syncthreads();
        rb[t] += add;
        __syncthreads();
    }
    int excl = rb[t] - myc;
    rb[t] = s0 + excl;
    if (base + t < N) rowptr[base + t] = s0 + excl;
    if (b == NB - 1 && t == 0) rowptr[N] = E;
    cntL[t] = 0;  // reuse as cursor
    __syncthreads();
    const int mask = (1 << PACK_SHIFT) - 1;
    for (int i = s0 + t; i < s1; i += 256) {
        int w = ebuf[i];
        int local = ((unsigned)w) >> PACK_SHIFT;
        int pos = rb[local] + atomicAdd(&cntL[local], 1);
        srcs[pos] = w & mask;
    }
}

// ---------------- tiled GEMM ----------------
// Y[M,64] = X[M,K] @ W[K,64], optional row-scale by dis[row].
// YT = unsigned short -> bf16 output; float -> fp32.
template<int K, bool SCALE, typename YT>
__global__ __launch_bounds__(256) void gemm_tiled(const float* __restrict__ X,
                                                  const float* __restrict__ W,
                                                  const float* __restrict__ dis,
                                                  YT* __restrict__ Y, int M) {
    __shared__ float Ws[K * 64];
    __shared__ float Xs[32 * 68];
    const int t = threadIdx.x;

    for (int i = t; i < K * 16; i += THREADS)
        ((float4*)Ws)[i] = ((const float4*)W)[i];

    const int r0 = blockIdx.x * 64;
    const int wave = t >> 6;
    const int lane = t & 63;
    const int tr = lane & 15;
    const int tc = (lane >> 4) + wave * 4;

    float acc[4][4] = {};

    for (int kc = 0; kc < K; kc += 32) {
        __syncthreads();
        #pragma unroll
        for (int i = t; i < 512; i += THREADS) {
            int row = i >> 3;
            int kq = i & 7;
            int gr = r0 + row;
            if (gr >= M) gr = M - 1;
            float4 v = *(const float4*)(X + (size_t)gr * K + kc + kq * 4);
            Xs[(kq * 4 + 0) * 68 + row] = v.x;
            Xs[(kq * 4 + 1) * 68 + row] = v.y;
            Xs[(kq * 4 + 2) * 68 + row] = v.z;
            Xs[(kq * 4 + 3) * 68 + row] = v.w;
        }
        __syncthreads();
        #pragma unroll
        for (int kk = 0; kk < 32; ++kk) {
            float4 xv = *(const float4*)(Xs + kk * 68 + tr * 4);
            float4 wv = *(const float4*)(Ws + (kc + kk) * 64 + tc * 4);
            acc[0][0] = fmaf(xv.x, wv.x, acc[0][0]);
            acc[0][1] = fmaf(xv.x, wv.y, acc[0][1]);
            acc[0][2] = fmaf(xv.x, wv.z, acc[0][2]);
            acc[0][3] = fmaf(xv.x, wv.w, acc[0][3]);
            acc[1][0] = fmaf(xv.y, wv.x, acc[1][0]);
            acc[1][1] = fmaf(xv.y, wv.y, acc[1][1]);
            acc[1][2] = fmaf(xv.y, wv.z, acc[1][2]);
            acc[1][3] = fmaf(xv.y, wv.w, acc[1][3]);
            acc[2][0] = fmaf(xv.z, wv.x, acc[2][0]);
            acc[2][1] = fmaf(xv.z, wv.y, acc[2][1]);
            acc[2][2] = fmaf(xv.z, wv.z, acc[2][2]);
            acc[2][3] = fmaf(xv.z, wv.w, acc[2][3]);
            acc[3][0] = fmaf(xv.w, wv.x, acc[3][0]);
            acc[3][1] = fmaf(xv.w, wv.y, acc[3][1]);
            acc[3][2] = fmaf(xv.w, wv.z, acc[3][2]);
            acc[3][3] = fmaf(xv.w, wv.w, acc[3][3]);
        }
    }

    #pragma unroll
    for (int i = 0; i < 4; ++i) {
        int row = r0 + tr * 4 + i;
        if (row < M) {
            float s = SCALE ? dis[row] : 1.0f;
            if constexpr (sizeof(YT) == 2) {
                ushort4 st;
                st.x = f2bf(acc[i][0] * s);
                st.y = f2bf(acc[i][1] * s);
                st.z = f2bf(acc[i][2] * s);
                st.w = f2bf(acc[i][3] * s);
                *(ushort4*)((unsigned short*)Y + (size_t)row * 64 + tc * 4) = st;
            } else {
                float4 st = make_float4(acc[i][0] * s, acc[i][1] * s,
                                        acc[i][2] * s, acc[i][3] * s);
                *(float4*)((float*)Y + (size_t)row * 64 + tc * 4) = st;
            }
        }
    }
}

// ---------------- pull aggregate: 2 nodes per wave (32-lane halves), bf16x2 loads ----
// HEAD=false: out[node][64] = relu(dis*agg + b)   (fp32)
// HEAD=true : s01[node] = {dot(h,Wh[0:64]), dot(h,Wh[64:128])}
template<bool HEAD>
__global__ __launch_bounds__(256) void pull2_kernel(const unsigned* __restrict__ hpre2,
                                                    const int* __restrict__ rowptr,
                                                    const int* __restrict__ srcs,
                                                    const float* __restrict__ dis,
                                                    const float* __restrict__ b,
                                                    const float* __restrict__ Wh,
                                                    float* __restrict__ out,
                                                    float2* __restrict__ s01, int N) {
    int tid = threadIdx.x;
    int wave = tid >> 6;
    int lane = tid & 63;
    int l = lane & 31;                       // feature-pair index: features 2l, 2l+1
    int node = blockIdx.x * 8 + wave * 2 + (lane >> 5);
    bool valid = node < N;
    int nc = valid ? node : N - 1;
    int i = rowptr[nc];
    int end = valid ? rowptr[nc + 1] : i;

    unsigned sv = hpre2[(size_t)nc * 32 + l];   // self loop
    float accx = bf2f_lo(sv), accy = bf2f_hi(sv);

    while (__any(i < end)) {
        #pragma unroll
        for (int k = 0; k < 8; ++k) {
            int idx = i + k;
            bool m = idx < end;
            int s = srcs[m ? idx : 0];          // done-half clamps to row 0 (cache-hot)
            unsigned v = hpre2[(size_t)s * 32 + l];
            accx += m ? bf2f_lo(v) : 0.f;
            accy += m ? bf2f_hi(v) : 0.f;
        }
        i += 8;
    }

    float d = dis[nc];
    float2 bb = ((const float2*)b)[l];
    float ox = accx * d + bb.x;
    float oy = accy * d + bb.y;
    ox = ox > 0.f ? ox : 0.f;
    oy = oy > 0.f ? oy : 0.f;

    if (HEAD) {
        float2 w0 = ((const float2*)Wh)[l];
        float2 w1 = ((const float2*)(Wh + 64))[l];
        float p0 = ox * w0.x + oy * w0.y;
        float p1 = ox * w1.x + oy * w1.y;
        #pragma unroll
        for (int off = 16; off > 0; off >>= 1) {
            p0 += __shfl_down(p0, off, 32);
            p1 += __shfl_down(p1, off, 32);
        }
        if (valid && l == 0) s01[node] = make_float2(p0, p1);
    } else {
        if (valid) *(float2*)(out + (size_t)node * 64 + 2 * l) = make_float2(ox, oy);
    }
}

// out[p] = s01[p0].x + s01[p1].y + bh  (s01 is ~800KB -> L2-resident gathers)
__global__ void pair_kernel(const float2* __restrict__ s01, const int* __restrict__ pairs,
                            const float* __restrict__ bh, float* __restrict__ out, int P) {
    int p = blockIdx.x * blockDim.x + threadIdx.x;
    if (p < P) {
        int p0 = pairs[2 * (size_t)p];
        int p1 = pairs[2 * (size_t)p + 1];
        out[p] = s01[p0].x + s01[p1].y + bh[0];
    }
}

// ---------------- fallback (atomic push, full fp32) ----------------
__global__ void degf_kernel(const int* __restrict__ dst, float* __restrict__ deg, int E) {
    int e = blockIdx.x * blockDim.x + threadIdx.x;
    if (e < E) atomicAdd(&deg[dst[e]], 1.0f);
}
__global__ void rsqrtf_kernel(float* deg, int N) {
    int i = blockIdx.x * blockDim.x + threadIdx.x;
    if (i < N) deg[i] = rsqrtf(deg[i] + 1.0f);
}
__global__ void scatter_kernel(const float* __restrict__ h, const int* __restrict__ src,
                               const int* __restrict__ dst, const float* __restrict__ dis,
                               float* __restrict__ agg, int E, int N) {
    long long idx = (long long)blockIdx.x * blockDim.x + threadIdx.x;
    int e = (int)(idx >> 6);
    int f = (int)(idx & 63);
    if (e >= E + N) return;
    int s, d;
    if (e < E) { s = src[e]; d = dst[e]; } else { s = e - E; d = s; }
    float norm = dis[s] * dis[d];
    atomicAdd(&agg[(size_t)d * 64 + f], h[(size_t)s * 64 + f] * norm);
}
__global__ void bias_relu_kernel(float* __restrict__ buf, const float* __restrict__ b,
                                 long long total) {
    long long i = (long long)blockIdx.x * blockDim.x + threadIdx.x;
    if (i < total) {
        float v = buf[i] + b[(int)(i & 63)];
        buf[i] = v > 0.f ? v : 0.f;
    }
}
__global__ void head_kernel(const float* __restrict__ h, const int* __restrict__ pairs,
                            const float* __restrict__ Wh, const float* __restrict__ bh,
                            float* __restrict__ out, int P) {
    long long idx = (long long)blockIdx.x * blockDim.x + threadIdx.x;
    int p = (int)(idx >> 6);
    int lane = threadIdx.x & 63;
    if (p >= P) return;
    int p0 = pairs[2 * (size_t)p];
    int p1 = pairs[2 * (size_t)p + 1];
    float v = h[(size_t)p0 * 64 + lane] * Wh[lane]
            + h[(size_t)p1 * 64 + lane] * Wh[64 + lane];
    #pragma unroll
    for (int off = 32; off > 0; off >>= 1) v += __shfl_down(v, off);
    if (lane == 0) out[p] = v + bh[0];
}

extern "C" void kernel_launch(void* const* d_in, const int* in_sizes, int n_in,
                              void* d_out, int out_size, void* d_ws, size_t ws_size,
                              hipStream_t stream) {
    const float* x     = (const float*)d_in[0];
    const int*   ei    = (const int*)d_in[1];   // [2,E]: row0=src, row1=dst
    const int*   pairs = (const int*)d_in[3];   // [P,2]
    const float* W1    = (const float*)d_in[4];
    const float* b1    = (const float*)d_in[5];
    const float* W2    = (const float*)d_in[6];
    const float* b2    = (const float*)d_in[7];
    const float* Wh    = (const float*)d_in[8];
    const float* bh    = (const float*)d_in[9];

    const int N = in_sizes[0] / 128;
    const int E = in_sizes[1] / 2;
    const int P = in_sizes[3] / 2;
    const int* srcArr = ei;
    const int* dstArr = ei + E;

    const size_t feat_total = (size_t)N * 64;
    const int NB = (N + BNODES - 1) / BNODES;      // dst buckets
    const int tileBlocks = (E + TILE - 1) / TILE;  // edge tiles
    const int gemm_blocks = (N + 63) / 64;
    const int pull_blocks = (N + 7) / 8;

    auto align512 = [](size_t v) { return (v + 511) & ~(size_t)511; };

    char* ws = (char*)d_ws;
    size_t off = 0;
    float*  dis    = (float*) (ws + off); off += align512((size_t)N * 4);
    int*    rowptr = (int*)   (ws + off); off += align512(((size_t)N + 1) * 4);
    int*    subcnt = (int*)   (ws + off); off += align512((size_t)NB * 4);
    int*    subcur = (int*)   (ws + off); off += align512((size_t)NB * 4);
    int*    subptr = (int*)   (ws + off); off += align512(((size_t)NB + 1) * 4);
    float2* s01    = (float2*)(ws + off); off += align512((size_t)N * 8);
    int*    srcs   = (int*)   (ws + off); off += align512((size_t)E * 4);
    // bufA slot holds: ebuf (E ints) early, then bf16 hpre [N][64]; sized for max.
    size_t bufA_bytes = align512((size_t)E * 4 > feat_total * 2 ? (size_t)E * 4
                                                                : feat_total * 2);
    unsigned short* bufA = (unsigned short*)(ws + off); off += bufA_bytes;
    float*  bufB   = (float*) (ws + off); off += align512(feat_total * 4);
    int*    ebuf   = (int*)bufA;  // aliased: consumed by bin_fill before gemm1 writes bufA
    const bool csr_ok = (off <= ws_size) && (NB <= 1024) && (N <= (1 << PACK_SHIFT));

    if (csr_ok) {
        // ---- CSR build ----
        hipMemsetAsync(subcnt, 0, (size_t)NB * 4, stream);
        hipMemsetAsync(subcur, 0, (size_t)NB * 4, stream);
        count_buckets<<<tileBlocks, 256, 0, stream>>>(dstArr, subcnt, NB, E);
        scan_small_kernel<<<1, 1024, 0, stream>>>(subcnt, subptr, NB, E);
        block_scatter<<<tileBlocks, 256, 0, stream>>>(srcArr, dstArr, subptr, subcur,
                                                      ebuf, NB, E);
        bin_fill_kernel<<<NB, 256, 0, stream>>>(ebuf, subptr, rowptr, dis, srcs, NB, N, E);

        // ---- layer 1: hpre(bf16) = (x@W1)*dis ; bufB(fp32) = relu(...) ----
        gemm_tiled<128, true, unsigned short><<<gemm_blocks, THREADS, 0, stream>>>(
            x, W1, dis, bufA, N);
        pull2_kernel<false><<<pull_blocks, THREADS, 0, stream>>>(
            (const unsigned*)bufA, rowptr, srcs, dis, b1, nullptr, bufB, nullptr, N);

        // ---- layer 2 + head dots fused ----
        gemm_tiled<64, true, unsigned short><<<gemm_blocks, THREADS, 0, stream>>>(
            bufB, W2, dis, bufA, N);
        pull2_kernel<true><<<pull_blocks, THREADS, 0, stream>>>(
            (const unsigned*)bufA, rowptr, srcs, dis, b2, Wh, nullptr, s01, N);

        // ---- pair gather ----
        pair_kernel<<<(P + THREADS - 1) / THREADS, THREADS, 0, stream>>>(
            s01, pairs, bh, (float*)d_out, P);
    } else {
        // ---- fallback: atomic push path, fp32 ----
        size_t o2 = 0;
        float* deg  = (float*)(ws + o2); o2 += align512((size_t)N * 4);
        float* bA   = (float*)(ws + o2); o2 += align512(feat_total * 4);
        float* bB   = (float*)(ws + o2);
        const size_t edge_threads = (size_t)(E + N) * 64;
        const int eblocks = (E + THREADS - 1) / THREADS;

        hipMemsetAsync(deg, 0, (size_t)N * 4, stream);
        degf_kernel<<<eblocks, THREADS, 0, stream>>>(dstArr, deg, E);
        rsqrtf_kernel<<<(N + THREADS - 1) / THREADS, THREADS, 0, stream>>>(deg, N);

        gemm_tiled<128, false, float><<<gemm_blocks, THREADS, 0, stream>>>(x, W1, deg, bA, N);
        hipMemsetAsync(bB, 0, feat_total * 4, stream);
        scatter_kernel<<<(unsigned)((edge_threads + THREADS - 1) / THREADS), THREADS, 0, stream>>>(
            bA, srcArr, dstArr, deg, bB, E, N);
        bias_relu_kernel<<<(unsigned)((feat_total + THREADS - 1) / THREADS), THREADS, 0, stream>>>(
            bB, b1, (long long)feat_total);

        gemm_tiled<64, false, float><<<gemm_blocks, THREADS, 0, stream>>>(bB, W2, deg, bA, N);
        hipMemsetAsync(bB, 0, feat_total * 4, stream);
        scatter_kernel<<<(unsigned)((edge_threads + THREADS - 1) / THREADS), THREADS, 0, stream>>>(
            bA, srcArr, dstArr, deg, bB, E, N);
        bias_relu_kernel<<<(unsigned)((feat_total + THREADS - 1) / THREADS), THREADS, 0, stream>>>(
            bB, b2, (long long)feat_total);

        head_kernel<<<(unsigned)(((size_t)P * 64 + THREADS - 1) / THREADS), THREADS, 0, stream>>>(
            bB, pairs, Wh, bh, (float*)d_out, P);
    }
}

// Round 9
// 198.791 us; speedup vs baseline: 2.9636x; 1.1836x over previous
//
#include <hip/hip_runtime.h>

#define THREADS 256
#define BNODES 256           // nodes per dst-bucket
#define PACK_SHIFT 20        // src in low 20 bits, local dst in bits 20..27
#define TILE 8192            // edges per block in count/scatter

__device__ __forceinline__ unsigned short f2bf(float f) {
    unsigned u = __float_as_uint(f);
    unsigned r = (u + 0x7fff + ((u >> 16) & 1)) >> 16;  // RNE
    return (unsigned short)r;
}
__device__ __forceinline__ float bf2f_lo(unsigned v) { return __uint_as_float(v << 16); }
__device__ __forceinline__ float bf2f_hi(unsigned v) { return __uint_as_float(v & 0xffff0000u); }

// ---------------- CSR build: block-binned counting sort, no per-edge global atomics ----

__global__ __launch_bounds__(256) void count_buckets(const int* __restrict__ dst,
                                                     int* __restrict__ subcnt,
                                                     int NB, int E) {
    __shared__ int h[1024];
    int t = threadIdx.x;
    for (int i = t; i < NB; i += 256) h[i] = 0;
    __syncthreads();
    int e0 = blockIdx.x * TILE;
    int e1 = min(e0 + TILE, E);
    for (int e = e0 + t; e < e1; e += 256)
        atomicAdd(&h[dst[e] >> 8], 1);
    __syncthreads();
    for (int i = t; i < NB; i += 256)
        if (h[i] > 0) atomicAdd(&subcnt[i], h[i]);
}

__global__ void scan_small_kernel(const int* __restrict__ cnt, int* __restrict__ ptr,
                                  int nb, int total) {
    __shared__ int sh[1024];
    int t = threadIdx.x;
    int v = (t < nb) ? cnt[t] : 0;
    sh[t] = v;
    __syncthreads();
    for (int off = 1; off < 1024; off <<= 1) {
        int add = (t >= off) ? sh[t - off] : 0;
        __syncthreads();
        sh[t] += add;
        __syncthreads();
    }
    if (t < nb) ptr[t] = sh[t] - v;
    if (t == 0) ptr[nb] = total;
}

__global__ __launch_bounds__(256) void block_scatter(const int* __restrict__ src,
                                                     const int* __restrict__ dst,
                                                     const int* __restrict__ subptr,
                                                     int* __restrict__ subcur,
                                                     int* __restrict__ ebuf,
                                                     int NB, int E) {
    __shared__ int h[1024];
    __shared__ int bb[1024];
    int t = threadIdx.x;
    for (int i = t; i < NB; i += 256) h[i] = 0;
    __syncthreads();
    int e0 = blockIdx.x * TILE;
    int e1 = min(e0 + TILE, E);
    for (int e = e0 + t; e < e1; e += 256)
        atomicAdd(&h[dst[e] >> 8], 1);
    __syncthreads();
    for (int i = t; i < NB; i += 256) {
        int c = h[i];
        bb[i] = (c > 0) ? (subptr[i] + atomicAdd(&subcur[i], c)) : 0;
        h[i] = 0;  // reuse as cursor
    }
    __syncthreads();
    for (int e = e0 + t; e < e1; e += 256) {
        int d = dst[e];
        int b = d >> 8;
        int pos = bb[b] + atomicAdd(&h[b], 1);
        ebuf[pos] = src[e] | ((d & (BNODES - 1)) << PACK_SHIFT);
    }
}

__global__ __launch_bounds__(256) void bin_fill_kernel(const int* __restrict__ ebuf,
                                                       const int* __restrict__ subptr,
                                                       int* __restrict__ rowptr,
                                                       float* __restrict__ dis,
                                                       int* __restrict__ srcs,
                                                       int NB, int N, int E) {
    __shared__ int cntL[BNODES];
    __shared__ int rb[BNODES];
    int b = blockIdx.x;
    int t = threadIdx.x;
    int base = b * BNODES;
    int s0 = subptr[b], s1 = subptr[b + 1];
    cntL[t] = 0;
    __syncthreads();
    for (int i = s0 + t; i < s1; i += 256)
        atomicAdd(&cntL[((unsigned)ebuf[i]) >> PACK_SHIFT], 1);
    __syncthreads();
    int myc = cntL[t];
    if (base + t < N) dis[base + t] = rsqrtf((float)myc + 1.0f);
    rb[t] = myc;
    __syncthreads();
    #pragma unroll
    for (int off = 1; off < 256; off <<= 1) {
        int add = (t >= off) ? rb[t - off] : 0;
        __syncthreads();
        rb[t] += add;
        __syncthreads();
    }
    int excl = rb[t] - myc;
    rb[t] = s0 + excl;
    if (base + t < N) rowptr[base + t] = s0 + excl;
    if (b == NB - 1 && t == 0) rowptr[N] = E;
    cntL[t] = 0;  // reuse as cursor
    __syncthreads();
    const int mask = (1 << PACK_SHIFT) - 1;
    for (int i = s0 + t; i < s1; i += 256) {
        int w = ebuf[i];
        int local = ((unsigned)w) >> PACK_SHIFT;
        int pos = rb[local] + atomicAdd(&cntL[local], 1);
        srcs[pos] = w & mask;
    }
}

// ---------------- tiled GEMM ----------------
// Y[M,64] = X[M,K] @ W[K,64], optional row-scale by dis[row].
// YT = unsigned short -> bf16 output; float -> fp32.
// Per-chunk W staging (8KB) + conflict-free Xs transpose stores + occupancy bound.
template<int K, bool SCALE, typename YT>
__global__ __launch_bounds__(256, 4) void gemm_tiled(const float* __restrict__ X,
                                                     const float* __restrict__ W,
                                                     const float* __restrict__ dis,
                                                     YT* __restrict__ Y, int M) {
    __shared__ float Ws[32 * 64];   // current K-chunk of W
    __shared__ float Xs[32 * 68];   // transposed X chunk [k][row], pitch 68
    const int t = threadIdx.x;

    const int r0 = blockIdx.x * 64;
    const int wave = t >> 6;
    const int lane = t & 63;
    const int tr = lane & 15;
    const int tc = (lane >> 4) + wave * 4;

    float acc[4][4] = {};

    #pragma unroll 1
    for (int kc = 0; kc < K; kc += 32) {
        __syncthreads();  // protect Ws/Xs from previous chunk's readers
        // stage W chunk [32][64] row-major: contiguous float4, conflict-free
        #pragma unroll
        for (int it = 0; it < 2; ++it) {
            int i = it * 256 + t;
            ((float4*)Ws)[i] = ((const float4*)(W + (size_t)kc * 64))[i];
        }
        // stage X chunk transposed: lane writes fixed k, consecutive rows -> no conflicts
        #pragma unroll
        for (int it = 0; it < 2; ++it) {
            int i = it * 256 + t;
            int row = i & 63;
            int kq = i >> 6;           // 0..7
            int gr = r0 + row;
            if (gr >= M) gr = M - 1;
            float4 v = *(const float4*)(X + (size_t)gr * K + kc + kq * 4);
            Xs[(kq * 4 + 0) * 68 + row] = v.x;
            Xs[(kq * 4 + 1) * 68 + row] = v.y;
            Xs[(kq * 4 + 2) * 68 + row] = v.z;
            Xs[(kq * 4 + 3) * 68 + row] = v.w;
        }
        __syncthreads();
        #pragma unroll
        for (int kk = 0; kk < 32; ++kk) {
            float4 xv = *(const float4*)(Xs + kk * 68 + tr * 4);
            float4 wv = *(const float4*)(Ws + kk * 64 + tc * 4);
            acc[0][0] = fmaf(xv.x, wv.x, acc[0][0]);
            acc[0][1] = fmaf(xv.x, wv.y, acc[0][1]);
            acc[0][2] = fmaf(xv.x, wv.z, acc[0][2]);
            acc[0][3] = fmaf(xv.x, wv.w, acc[0][3]);
            acc[1][0] = fmaf(xv.y, wv.x, acc[1][0]);
            acc[1][1] = fmaf(xv.y, wv.y, acc[1][1]);
            acc[1][2] = fmaf(xv.y, wv.z, acc[1][2]);
            acc[1][3] = fmaf(xv.y, wv.w, acc[1][3]);
            acc[2][0] = fmaf(xv.z, wv.x, acc[2][0]);
            acc[2][1] = fmaf(xv.z, wv.y, acc[2][1]);
            acc[2][2] = fmaf(xv.z, wv.z, acc[2][2]);
            acc[2][3] = fmaf(xv.z, wv.w, acc[2][3]);
            acc[3][0] = fmaf(xv.w, wv.x, acc[3][0]);
            acc[3][1] = fmaf(xv.w, wv.y, acc[3][1]);
            acc[3][2] = fmaf(xv.w, wv.z, acc[3][2]);
            acc[3][3] = fmaf(xv.w, wv.w, acc[3][3]);
        }
    }

    #pragma unroll
    for (int i = 0; i < 4; ++i) {
        int row = r0 + tr * 4 + i;
        if (row < M) {
            float s = SCALE ? dis[row] : 1.0f;
            if constexpr (sizeof(YT) == 2) {
                ushort4 st;
                st.x = f2bf(acc[i][0] * s);
                st.y = f2bf(acc[i][1] * s);
                st.z = f2bf(acc[i][2] * s);
                st.w = f2bf(acc[i][3] * s);
                *(ushort4*)((unsigned short*)Y + (size_t)row * 64 + tc * 4) = st;
            } else {
                float4 st = make_float4(acc[i][0] * s, acc[i][1] * s,
                                        acc[i][2] * s, acc[i][3] * s);
                *(float4*)((float*)Y + (size_t)row * 64 + tc * 4) = st;
            }
        }
    }
}

// ---------------- pull aggregate: 2 nodes per wave (32-lane halves), bf16x2 loads ----
// HEAD=false: out[node][64] = relu(dis*agg + b)   (fp32)
// HEAD=true : s01[node] = {dot(h,Wh[0:64]), dot(h,Wh[64:128])}
template<bool HEAD>
__global__ __launch_bounds__(256) void pull2_kernel(const unsigned* __restrict__ hpre2,
                                                    const int* __restrict__ rowptr,
                                                    const int* __restrict__ srcs,
                                                    const float* __restrict__ dis,
                                                    const float* __restrict__ b,
                                                    const float* __restrict__ Wh,
                                                    float* __restrict__ out,
                                                    float2* __restrict__ s01, int N) {
    int tid = threadIdx.x;
    int wave = tid >> 6;
    int lane = tid & 63;
    int l = lane & 31;                       // feature-pair index: features 2l, 2l+1
    int node = blockIdx.x * 8 + wave * 2 + (lane >> 5);
    bool valid = node < N;
    int nc = valid ? node : N - 1;
    int i = rowptr[nc];
    int end = valid ? rowptr[nc + 1] : i;

    unsigned sv = hpre2[(size_t)nc * 32 + l];   // self loop
    float accx = bf2f_lo(sv), accy = bf2f_hi(sv);

    while (__any(i < end)) {
        #pragma unroll
        for (int k = 0; k < 8; ++k) {
            int idx = i + k;
            bool m = idx < end;
            int s = srcs[m ? idx : 0];          // done-half clamps to row 0 (cache-hot)
            unsigned v = hpre2[(size_t)s * 32 + l];
            accx += m ? bf2f_lo(v) : 0.f;
            accy += m ? bf2f_hi(v) : 0.f;
        }
        i += 8;
    }

    float d = dis[nc];
    float2 bb = ((const float2*)b)[l];
    float ox = accx * d + bb.x;
    float oy = accy * d + bb.y;
    ox = ox > 0.f ? ox : 0.f;
    oy = oy > 0.f ? oy : 0.f;

    if (HEAD) {
        float2 w0 = ((const float2*)Wh)[l];
        float2 w1 = ((const float2*)(Wh + 64))[l];
        float p0 = ox * w0.x + oy * w0.y;
        float p1 = ox * w1.x + oy * w1.y;
        #pragma unroll
        for (int off = 16; off > 0; off >>= 1) {
            p0 += __shfl_down(p0, off, 32);
            p1 += __shfl_down(p1, off, 32);
        }
        if (valid && l == 0) s01[node] = make_float2(p0, p1);
    } else {
        if (valid) *(float2*)(out + (size_t)node * 64 + 2 * l) = make_float2(ox, oy);
    }
}

// out[p] = s01[p0].x + s01[p1].y + bh  (s01 is ~800KB -> L2-resident gathers)
__global__ void pair_kernel(const float2* __restrict__ s01, const int* __restrict__ pairs,
                            const float* __restrict__ bh, float* __restrict__ out, int P) {
    int p = blockIdx.x * blockDim.x + threadIdx.x;
    if (p < P) {
        int p0 = pairs[2 * (size_t)p];
        int p1 = pairs[2 * (size_t)p + 1];
        out[p] = s01[p0].x + s01[p1].y + bh[0];
    }
}

// ---------------- fallback (atomic push, full fp32) ----------------
__global__ void degf_kernel(const int* __restrict__ dst, float* __restrict__ deg, int E) {
    int e = blockIdx.x * blockDim.x + threadIdx.x;
    if (e < E) atomicAdd(&deg[dst[e]], 1.0f);
}
__global__ void rsqrtf_kernel(float* deg, int N) {
    int i = blockIdx.x * blockDim.x + threadIdx.x;
    if (i < N) deg[i] = rsqrtf(deg[i] + 1.0f);
}
__global__ void scatter_kernel(const float* __restrict__ h, const int* __restrict__ src,
                               const int* __restrict__ dst, const float* __restrict__ dis,
                               float* __restrict__ agg, int E, int N) {
    long long idx = (long long)blockIdx.x * blockDim.x + threadIdx.x;
    int e = (int)(idx >> 6);
    int f = (int)(idx & 63);
    if (e >= E + N) return;
    int s, d;
    if (e < E) { s = src[e]; d = dst[e]; } else { s = e - E; d = s; }
    float norm = dis[s] * dis[d];
    atomicAdd(&agg[(size_t)d * 64 + f], h[(size_t)s * 64 + f] * norm);
}
__global__ void bias_relu_kernel(float* __restrict__ buf, const float* __restrict__ b,
                                 long long total) {
    long long i = (long long)blockIdx.x * blockDim.x + threadIdx.x;
    if (i < total) {
        float v = buf[i] + b[(int)(i & 63)];
        buf[i] = v > 0.f ? v : 0.f;
    }
}
__global__ void head_kernel(const float* __restrict__ h, const int* __restrict__ pairs,
                            const float* __restrict__ Wh, const float* __restrict__ bh,
                            float* __restrict__ out, int P) {
    long long idx = (long long)blockIdx.x * blockDim.x + threadIdx.x;
    int p = (int)(idx >> 6);
    int lane = threadIdx.x & 63;
    if (p >= P) return;
    int p0 = pairs[2 * (size_t)p];
    int p1 = pairs[2 * (size_t)p + 1];
    float v = h[(size_t)p0 * 64 + lane] * Wh[lane]
            + h[(size_t)p1 * 64 + lane] * Wh[64 + lane];
    #pragma unroll
    for (int off = 32; off > 0; off >>= 1) v += __shfl_down(v, off);
    if (lane == 0) out[p] = v + bh[0];
}

extern "C" void kernel_launch(void* const* d_in, const int* in_sizes, int n_in,
                              void* d_out, int out_size, void* d_ws, size_t ws_size,
                              hipStream_t stream) {
    const float* x     = (const float*)d_in[0];
    const int*   ei    = (const int*)d_in[1];   // [2,E]: row0=src, row1=dst
    const int*   pairs = (const int*)d_in[3];   // [P,2]
    const float* W1    = (const float*)d_in[4];
    const float* b1    = (const float*)d_in[5];
    const float* W2    = (const float*)d_in[6];
    const float* b2    = (const float*)d_in[7];
    const float* Wh    = (const float*)d_in[8];
    const float* bh    = (const float*)d_in[9];

    const int N = in_sizes[0] / 128;
    const int E = in_sizes[1] / 2;
    const int P = in_sizes[3] / 2;
    const int* srcArr = ei;
    const int* dstArr = ei + E;

    const size_t feat_total = (size_t)N * 64;
    const int NB = (N + BNODES - 1) / BNODES;      // dst buckets
    const int tileBlocks = (E + TILE - 1) / TILE;  // edge tiles
    const int gemm_blocks = (N + 63) / 64;
    const int pull_blocks = (N + 7) / 8;

    auto align512 = [](size_t v) { return (v + 511) & ~(size_t)511; };

    char* ws = (char*)d_ws;
    size_t off = 0;
    float*  dis    = (float*) (ws + off); off += align512((size_t)N * 4);
    int*    rowptr = (int*)   (ws + off); off += align512(((size_t)N + 1) * 4);
    int*    subcnt = (int*)   (ws + off); off += align512((size_t)NB * 4);
    int*    subcur = (int*)   (ws + off); off += align512((size_t)NB * 4);
    int*    subptr = (int*)   (ws + off); off += align512(((size_t)NB + 1) * 4);
    float2* s01    = (float2*)(ws + off); off += align512((size_t)N * 8);
    int*    srcs   = (int*)   (ws + off); off += align512((size_t)E * 4);
    // bufA slot holds: ebuf (E ints) early, then bf16 hpre [N][64]; sized for max.
    size_t bufA_bytes = align512((size_t)E * 4 > feat_total * 2 ? (size_t)E * 4
                                                                : feat_total * 2);
    unsigned short* bufA = (unsigned short*)(ws + off); off += bufA_bytes;
    float*  bufB   = (float*) (ws + off); off += align512(feat_total * 4);
    int*    ebuf   = (int*)bufA;  // aliased: consumed by bin_fill before gemm1 writes bufA
    const bool csr_ok = (off <= ws_size) && (NB <= 1024) && (N <= (1 << PACK_SHIFT));

    if (csr_ok) {
        // ---- CSR build ----
        hipMemsetAsync(subcnt, 0, (size_t)NB * 4, stream);
        hipMemsetAsync(subcur, 0, (size_t)NB * 4, stream);
        count_buckets<<<tileBlocks, 256, 0, stream>>>(dstArr, subcnt, NB, E);
        scan_small_kernel<<<1, 1024, 0, stream>>>(subcnt, subptr, NB, E);
        block_scatter<<<tileBlocks, 256, 0, stream>>>(srcArr, dstArr, subptr, subcur,
                                                      ebuf, NB, E);
        bin_fill_kernel<<<NB, 256, 0, stream>>>(ebuf, subptr, rowptr, dis, srcs, NB, N, E);

        // ---- layer 1: hpre(bf16) = (x@W1)*dis ; bufB(fp32) = relu(...) ----
        gemm_tiled<128, true, unsigned short><<<gemm_blocks, THREADS, 0, stream>>>(
            x, W1, dis, bufA, N);
        pull2_kernel<false><<<pull_blocks, THREADS, 0, stream>>>(
            (const unsigned*)bufA, rowptr, srcs, dis, b1, nullptr, bufB, nullptr, N);

        // ---- layer 2 + head dots fused ----
        gemm_tiled<64, true, unsigned short><<<gemm_blocks, THREADS, 0, stream>>>(
            bufB, W2, dis, bufA, N);
        pull2_kernel<true><<<pull_blocks, THREADS, 0, stream>>>(
            (const unsigned*)bufA, rowptr, srcs, dis, b2, Wh, nullptr, s01, N);

        // ---- pair gather ----
        pair_kernel<<<(P + THREADS - 1) / THREADS, THREADS, 0, stream>>>(
            s01, pairs, bh, (float*)d_out, P);
    } else {
        // ---- fallback: atomic push path, fp32 ----
        size_t o2 = 0;
        float* deg  = (float*)(ws + o2); o2 += align512((size_t)N * 4);
        float* bA   = (float*)(ws + o2); o2 += align512(feat_total * 4);
        float* bB   = (float*)(ws + o2);
        const size_t edge_threads = (size_t)(E + N) * 64;
        const int eblocks = (E + THREADS - 1) / THREADS;

        hipMemsetAsync(deg, 0, (size_t)N * 4, stream);
        degf_kernel<<<eblocks, THREADS, 0, stream>>>(dstArr, deg, E);
        rsqrtf_kernel<<<(N + THREADS - 1) / THREADS, THREADS, 0, stream>>>(deg, N);

        gemm_tiled<128, false, float><<<gemm_blocks, THREADS, 0, stream>>>(x, W1, deg, bA, N);
        hipMemsetAsync(bB, 0, feat_total * 4, stream);
        scatter_kernel<<<(unsigned)((edge_threads + THREADS - 1) / THREADS), THREADS, 0, stream>>>(
            bA, srcArr, dstArr, deg, bB, E, N);
        bias_relu_kernel<<<(unsigned)((feat_total + THREADS - 1) / THREADS), THREADS, 0, stream>>>(
            bB, b1, (long long)feat_total);

        gemm_tiled<64, false, float><<<gemm_blocks, THREADS, 0, stream>>>(bB, W2, deg, bA, N);
        hipMemsetAsync(bB, 0, feat_total * 4, stream);
        scatter_kernel<<<(unsigned)((edge_threads + THREADS - 1) / THREADS), THREADS, 0, stream>>>(
            bA, srcArr, dstArr, deg, bB, E, N);
        bias_relu_kernel<<<(unsigned)((feat_total + THREADS - 1) / THREADS), THREADS, 0, stream>>>(
            bB, b2, (long long)feat_total);

        head_kernel<<<(unsigned)(((size_t)P * 64 + THREADS - 1) / THREADS), THREADS, 0, stream>>>(
            bB, pairs, Wh, bh, (float*)d_out, P);
    }
}